// Round 7
// baseline (194.149 us; speedup 1.0000x reference)
//
#include <hip/hip_runtime.h>

#define EPS 1e-5f

constexpr int FIN = 22;   // input feature dim
constexpr int XP  = 32;   // padded x feature stride
constexpr int H   = 128;  // hidden dim
constexpr int SLICE_SHIFT = 17;  // 131072 CSR entries (512KB) per slice
constexpr int EPB = 2048;        // edges per scatter block-chunk

// bf16 helpers (bit-level, RN-even)
static __device__ __forceinline__ unsigned short f2bf(float f) {
    unsigned int u = __float_as_uint(f);
    unsigned int r = (u + 0x7fffu + ((u >> 16) & 1u)) >> 16;
    return (unsigned short)r;
}
static __device__ __forceinline__ float bflo(unsigned int u) {  // low bf16 of a dword
    return __uint_as_float(u << 16);
}
static __device__ __forceinline__ float bfhi(unsigned int u) {  // high bf16 of a dword
    return __uint_as_float(u & 0xffff0000u);
}

// ---------------- degree + in-edge rank (one atomic pass); prep folded into block 0 ----------------
__global__ void rank_kernel(const int* __restrict__ ei, int* __restrict__ degi,
                            int* __restrict__ rank, int E,
                            const float* __restrict__ b1, const float* __restrict__ mean1,
                            const float* __restrict__ var1, const float* __restrict__ gamma1,
                            const float* __restrict__ beta1,
                            const float* __restrict__ b2, const float* __restrict__ mean2,
                            const float* __restrict__ var2, const float* __restrict__ gamma2,
                            const float* __restrict__ beta2,
                            float* __restrict__ A1f, float* __restrict__ B1f,
                            float* __restrict__ A2f, float* __restrict__ B2f) {
    int e = blockIdx.x * blockDim.x + threadIdx.x;
    if (e < E) rank[e] = atomicAdd(&degi[ei[E + e]], 1);
    if (blockIdx.x == 0 && threadIdx.x < H) {
        int t = threadIdx.x;
        float A1 = gamma1[t] * rsqrtf(var1[t] + EPS);
        A1f[t] = A1;
        B1f[t] = (b1[t] - mean1[t]) * A1 + beta1[t];
        float A2 = gamma2[t] * rsqrtf(var2[t] + EPS);
        A2f[t] = A2;
        B2f[t] = (b2[t] - mean2[t]) * A2 + beta2[t];
    }
}

// ---------------- scan phase A: per-block exclusive scan + dinv + xr = bf16(x*dinv) ----------------
__global__ __launch_bounds__(256) void scanA_kernel(
    const int* __restrict__ degi, const float* __restrict__ x,
    int* __restrict__ offs, int* __restrict__ bsum,
    float* __restrict__ dinv, unsigned short* __restrict__ xb, int N) {
    __shared__ int sh[256];
    const int t = threadIdx.x;
    const int i = blockIdx.x * 256 + t;
    int v = (i < N) ? degi[i] : 0;
    sh[t] = v;
    __syncthreads();
    int val = v;
    for (int off = 1; off < 256; off <<= 1) {
        int add = (t >= off) ? sh[t - off] : 0;
        __syncthreads();
        val += add;
        sh[t] = val;
        __syncthreads();
    }
    if (i < N) offs[i] = val - v;          // exclusive within block (global base added by consumers)
    if (t == 255) bsum[blockIdx.x] = val;  // block total
    if (i < N) {
        float di = rsqrtf((float)v + 1.0f); // +1 self-loop
        dinv[i] = di;
#pragma unroll
        for (int k = 0; k < XP; ++k)
            xb[i * XP + k] = (k < FIN) ? f2bf(x[i * FIN + k] * di) : (unsigned short)0;
    }
}

// ---------------- scan phase B: exclusive scan of block sums ----------------
__global__ __launch_bounds__(256) void scanB_kernel(int* __restrict__ bsum, int nb) {
    __shared__ int sh[256];
    const int t = threadIdx.x;
    int v = (t < nb) ? bsum[t] : 0;
    sh[t] = v;
    __syncthreads();
    int val = v;
    for (int off = 1; off < 256; off <<= 1) {
        int add = (t >= off) ? sh[t - off] : 0;
        __syncthreads();
        val += add;
        sh[t] = val;
        __syncthreads();
    }
    if (t < nb) bsum[t] = val - v;
}

// global CSR start of node i = offs[i] + bsum[i>>8]; end of last node = E
static __device__ __forceinline__ int off_at(const int* __restrict__ offs,
                                             const int* __restrict__ bsum,
                                             int i, int N, int E) {
    return (i < N) ? offs[i] + bsum[i >> 8] : E;
}

// ---------------- XCD-sliced CSR scatter ----------------
// grid = ceil(E/EPB)*8; r = blockIdx&7 targets XCD r (round-robin heuristic).
// Block stores only positions in slice r -> each 512KB slice written by one XCD,
// lines accumulate all slot-writes in that XCD's L2 before one writeback.
__global__ __launch_bounds__(256) void scatter8_kernel(
    const int* __restrict__ ei, const int* __restrict__ rank,
    const int* __restrict__ offs, const int* __restrict__ bsum,
    int* __restrict__ csrS, int E, int nslice) {
    const int r = blockIdx.x & 7;
    if (r >= nslice) return;
    const int chunk = blockIdx.x >> 3;
    const int e1 = min(chunk * EPB + EPB, E);
    for (int e = chunk * EPB + threadIdx.x; e < e1; e += 256) {
        int d = ei[E + e];
        int p = offs[d] + bsum[d >> 8] + rank[e];
        if ((p >> SLICE_SHIFT) == r) csrS[p] = ei[e];
    }
}
// CSR range of node d = [ off_at(d), off_at(d+1) )

// ---------------- layer-1 gather: unweighted sum of pre-scaled rows, *dinv at end ----------------
// wave = 8 groups x 8 lanes; 2-edge unrolled body for MLP
__global__ __launch_bounds__(256) void gather_x_kernel(
    const unsigned short* __restrict__ xb, const float* __restrict__ dinv,
    const int* __restrict__ offs, const int* __restrict__ bsum,
    const int* __restrict__ csrS, float* __restrict__ xa, int N) {
    const int tid  = threadIdx.x;
    const int node = blockIdx.x * 4 + (tid >> 6);
    const int lane = tid & 63;
    if (node >= N) return;
    const int g  = lane >> 3;      // group 0..7
    const int fl = lane & 7;       // lane in group
    const int beg = off_at(offs, bsum, node, N, 0x7fffffff);
    const int end = off_at(offs, bsum, node + 1, N, beg);  // E bound via offs[N-1]+... ; node+1<=N

    float acc0 = 0.f, acc1 = 0.f, acc2 = 0.f, acc3 = 0.f;
    if (g == 0) {  // self row, weight 1 (own dinv already folded in)
        ushort4 v = *reinterpret_cast<const ushort4*>(xb + (size_t)node * XP + fl * 4);
        acc0 = bflo(v.x); acc1 = bflo(v.y);
        acc2 = bflo(v.z); acc3 = bflo(v.w);
    }
    int e = beg + g;
    for (; e + 8 < end; e += 16) {
        int s0 = csrS[e];
        int s1 = csrS[e + 8];
        ushort4 v0 = *reinterpret_cast<const ushort4*>(xb + (size_t)s0 * XP + fl * 4);
        ushort4 v1 = *reinterpret_cast<const ushort4*>(xb + (size_t)s1 * XP + fl * 4);
        acc0 += bflo(v0.x) + bflo(v1.x);
        acc1 += bflo(v0.y) + bflo(v1.y);
        acc2 += bflo(v0.z) + bflo(v1.z);
        acc3 += bflo(v0.w) + bflo(v1.w);
    }
    if (e < end) {
        int s = csrS[e];
        ushort4 v = *reinterpret_cast<const ushort4*>(xb + (size_t)s * XP + fl * 4);
        acc0 += bflo(v.x); acc1 += bflo(v.y);
        acc2 += bflo(v.z); acc3 += bflo(v.w);
    }
#pragma unroll
    for (int off = 8; off < 64; off <<= 1) {
        acc0 += __shfl_xor(acc0, off);
        acc1 += __shfl_xor(acc1, off);
        acc2 += __shfl_xor(acc2, off);
        acc3 += __shfl_xor(acc3, off);
    }
    if (g == 0) {
        float di = dinv[node];
        float4 o = make_float4(acc0 * di, acc1 * di, acc2 * di, acc3 * di);
        *reinterpret_cast<float4*>(xa + (size_t)node * XP + fl * 4) = o;
    }
}

// ---------------- fused gemm1+BN1+ReLU+gemm2 (h1 stays in LDS); h2r = h2*A2*dinv ----------------
__global__ __launch_bounds__(256) void gemm12_kernel(
    const float* __restrict__ xa, const float* __restrict__ W1, const float* __restrict__ W2,
    const float* __restrict__ A1f, const float* __restrict__ B1f, const float* __restrict__ A2f,
    const float* __restrict__ dinv, unsigned short* __restrict__ h2b, int N) {
    __shared__ float lds1[16 * XP];        // xa tile
    __shared__ float lds2[H * 20];         // h1 tile, transposed [k][row], pad 20
    const int tid = threadIdx.x;
    const int m0  = blockIdx.x * 16;

    for (int idx = tid; idx < 16 * XP; idx += 256) {
        int row = m0 + (idx >> 5);
        lds1[idx] = (row < N) ? xa[(size_t)m0 * XP + idx] : 0.0f;
    }
    __syncthreads();

    const int f  = tid & 127;
    const int mg = tid >> 7;

    // gemm1
    float acc1[8];
#pragma unroll
    for (int j = 0; j < 8; ++j) acc1[j] = 0.0f;
    for (int k = 0; k < FIN; ++k) {
        float w = W1[k * H + f];
#pragma unroll
        for (int j = 0; j < 8; ++j) acc1[j] += lds1[(mg * 8 + j) * XP + k] * w;
    }
    const float A1 = A1f[f], B1 = B1f[f];
    float4 h1a, h1b;
    h1a.x = fmaxf(acc1[0] * A1 + B1, 0.f); h1a.y = fmaxf(acc1[1] * A1 + B1, 0.f);
    h1a.z = fmaxf(acc1[2] * A1 + B1, 0.f); h1a.w = fmaxf(acc1[3] * A1 + B1, 0.f);
    h1b.x = fmaxf(acc1[4] * A1 + B1, 0.f); h1b.y = fmaxf(acc1[5] * A1 + B1, 0.f);
    h1b.z = fmaxf(acc1[6] * A1 + B1, 0.f); h1b.w = fmaxf(acc1[7] * A1 + B1, 0.f);
    *reinterpret_cast<float4*>(&lds2[f * 20 + mg * 8])     = h1a;
    *reinterpret_cast<float4*>(&lds2[f * 20 + mg * 8 + 4]) = h1b;
    __syncthreads();

    // gemm2
    float acc2[8];
#pragma unroll
    for (int j = 0; j < 8; ++j) acc2[j] = 0.0f;
    for (int k = 0; k < H; ++k) {
        float w = W2[k * H + f];
        float4 ha = *reinterpret_cast<const float4*>(&lds2[k * 20 + mg * 8]);
        float4 hb = *reinterpret_cast<const float4*>(&lds2[k * 20 + mg * 8 + 4]);
        acc2[0] += ha.x * w; acc2[1] += ha.y * w; acc2[2] += ha.z * w; acc2[3] += ha.w * w;
        acc2[4] += hb.x * w; acc2[5] += hb.y * w; acc2[6] += hb.z * w; acc2[7] += hb.w * w;
    }
    const float A2 = A2f[f];
#pragma unroll
    for (int j = 0; j < 8; ++j) {
        int node = m0 + mg * 8 + j;
        if (node < N) {
            float sc = A2 * dinv[node];   // fold own dinv into stored row
            h2b[(size_t)node * H + f] = f2bf(acc2[j] * sc);
        }
    }
}

// ---------------- fused: layer-2 gather (pure row sum) + BN2 + ReLU + FC + sigmoid ----------------
// wave = 4 groups x 16 lanes; 4-edge unrolled body for MLP (4 x 256B rows in flight/group)
__global__ __launch_bounds__(256) void gfinal_kernel(
    const unsigned short* __restrict__ h2b, const float* __restrict__ dinv,
    const int* __restrict__ offs, const int* __restrict__ bsum,
    const int* __restrict__ csrS,
    const float* __restrict__ B2f, const float* __restrict__ Wfc,
    const float* __restrict__ bfc, float* __restrict__ out, int N) {
    const int tid  = threadIdx.x;
    const int node = blockIdx.x * 4 + (tid >> 6);
    const int lane = tid & 63;
    if (node >= N) return;
    const int g  = lane >> 4;      // group 0..3
    const int fl = lane & 15;      // lane in group
    const int f0 = fl * 8;
    const int beg = off_at(offs, bsum, node, N, 0x7fffffff);
    const int end = off_at(offs, bsum, node + 1, N, beg);

    float acc[8];
#pragma unroll
    for (int j = 0; j < 8; ++j) acc[j] = 0.0f;

    if (g == 0) {  // self row, weight 1
        uint4 v = *reinterpret_cast<const uint4*>(h2b + (size_t)node * H + f0);
        acc[0] = bflo(v.x); acc[1] = bfhi(v.x);
        acc[2] = bflo(v.y); acc[3] = bfhi(v.y);
        acc[4] = bflo(v.z); acc[5] = bfhi(v.z);
        acc[6] = bflo(v.w); acc[7] = bfhi(v.w);
    }
    int e = beg + g;
    for (; e + 12 < end; e += 16) {  // 4 rows in flight
        int s0 = csrS[e];
        int s1 = csrS[e + 4];
        int s2 = csrS[e + 8];
        int s3 = csrS[e + 12];
        uint4 v0 = *reinterpret_cast<const uint4*>(h2b + (size_t)s0 * H + f0);
        uint4 v1 = *reinterpret_cast<const uint4*>(h2b + (size_t)s1 * H + f0);
        uint4 v2 = *reinterpret_cast<const uint4*>(h2b + (size_t)s2 * H + f0);
        uint4 v3 = *reinterpret_cast<const uint4*>(h2b + (size_t)s3 * H + f0);
        acc[0] += (bflo(v0.x) + bflo(v1.x)) + (bflo(v2.x) + bflo(v3.x));
        acc[1] += (bfhi(v0.x) + bfhi(v1.x)) + (bfhi(v2.x) + bfhi(v3.x));
        acc[2] += (bflo(v0.y) + bflo(v1.y)) + (bflo(v2.y) + bflo(v3.y));
        acc[3] += (bfhi(v0.y) + bfhi(v1.y)) + (bfhi(v2.y) + bfhi(v3.y));
        acc[4] += (bflo(v0.z) + bflo(v1.z)) + (bflo(v2.z) + bflo(v3.z));
        acc[5] += (bfhi(v0.z) + bfhi(v1.z)) + (bfhi(v2.z) + bfhi(v3.z));
        acc[6] += (bflo(v0.w) + bflo(v1.w)) + (bflo(v2.w) + bflo(v3.w));
        acc[7] += (bfhi(v0.w) + bfhi(v1.w)) + (bfhi(v2.w) + bfhi(v3.w));
    }
    for (; e < end; e += 4) {
        int s = csrS[e];
        uint4 v = *reinterpret_cast<const uint4*>(h2b + (size_t)s * H + f0);
        acc[0] += bflo(v.x); acc[1] += bfhi(v.x);
        acc[2] += bflo(v.y); acc[3] += bfhi(v.y);
        acc[4] += bflo(v.z); acc[5] += bfhi(v.z);
        acc[6] += bflo(v.w); acc[7] += bfhi(v.w);
    }
#pragma unroll
    for (int j = 0; j < 8; ++j) {
        acc[j] += __shfl_xor(acc[j], 16);
        acc[j] += __shfl_xor(acc[j], 32);
    }
    const float di = dinv[node];
    float p = 0.0f;
#pragma unroll
    for (int j = 0; j < 8; ++j)
        p += fmaxf(acc[j] * di + B2f[f0 + j], 0.0f) * Wfc[f0 + j];
#pragma unroll
    for (int off = 1; off < 16; off <<= 1) p += __shfl_xor(p, off);
    if (lane == 0) out[node] = 1.0f / (1.0f + expf(-(p + bfc[0])));
}

static inline size_t align4w(size_t w) { return (w + 3) & ~(size_t)3; }  // 16B align (words)

extern "C" void kernel_launch(void* const* d_in, const int* in_sizes, int n_in,
                              void* d_out, int out_size, void* d_ws, size_t ws_size,
                              hipStream_t stream) {
    const float* x      = (const float*)d_in[0];
    const int*   ei     = (const int*)d_in[1];
    const float* W1     = (const float*)d_in[2];
    const float* b1     = (const float*)d_in[3];
    const float* gamma1 = (const float*)d_in[4];
    const float* beta1  = (const float*)d_in[5];
    const float* mean1  = (const float*)d_in[6];
    const float* var1   = (const float*)d_in[7];
    const float* W2     = (const float*)d_in[8];
    const float* b2     = (const float*)d_in[9];
    const float* gamma2 = (const float*)d_in[10];
    const float* beta2  = (const float*)d_in[11];
    const float* mean2  = (const float*)d_in[12];
    const float* var2   = (const float*)d_in[13];
    const float* Wfc    = (const float*)d_in[14];
    const float* bfc    = (const float*)d_in[15];
    float* out = (float*)d_out;

    const int N = in_sizes[0] / FIN;   // 50000
    const int E = in_sizes[1] / 2;     // 800000
    const int NB = (N + 255) / 256;
    const int nslice = (E + (1 << SLICE_SHIFT) - 1) >> SLICE_SHIFT;  // 7 for E=800000

    // workspace layout (4-byte words, 16B-aligned sections)
    int* base = (int*)d_ws;
    size_t o = 0;
    int*   degi = base + o;                o = align4w(o + N);
    float* dinv = (float*)(base + o);      o = align4w(o + N);
    int*   offs = base + o;                o = align4w(o + N + 1);
    int*   bsum = base + o;                o = align4w(o + 256);
    float* A1f  = (float*)(base + o);      o = align4w(o + H);
    float* B1f  = (float*)(base + o);      o = align4w(o + H);
    float* A2f  = (float*)(base + o);      o = align4w(o + H);
    float* B2f  = (float*)(base + o);      o = align4w(o + H);
    int*   rank = base + o;                o = align4w(o + (size_t)E);
    int*   csrS = base + o;                o = align4w(o + (size_t)E);
    unsigned short* xb = (unsigned short*)(base + o); o = align4w(o + (size_t)N * XP / 2);
    float* xa   = (float*)(base + o);      o = align4w(o + (size_t)N * XP);
    unsigned short* h2b = (unsigned short*)(base + o);

    hipMemsetAsync(degi, 0, (size_t)N * sizeof(int), stream);

    rank_kernel<<<(E + 255) / 256, 256, 0, stream>>>(
        ei, degi, rank, E,
        b1, mean1, var1, gamma1, beta1, b2, mean2, var2, gamma2, beta2,
        A1f, B1f, A2f, B2f);
    scanA_kernel<<<NB, 256, 0, stream>>>(degi, x, offs, bsum, dinv, xb, N);
    scanB_kernel<<<1, 256, 0, stream>>>(bsum, NB);
    scatter8_kernel<<<((E + EPB - 1) / EPB) * 8, 256, 0, stream>>>(
        ei, rank, offs, bsum, csrS, E, nslice);

    gather_x_kernel<<<(N + 3) / 4, 256, 0, stream>>>(xb, dinv, offs, bsum, csrS, xa, N);
    gemm12_kernel<<<(N + 15) / 16, 256, 0, stream>>>(xa, W1, W2, A1f, B1f, A2f, dinv, h2b, N);
    gfinal_kernel<<<(N + 3) / 4, 256, 0, stream>>>(h2b, dinv, offs, bsum, csrS, B2f, Wfc, bfc, out, N);
}

// Round 8
// 177.215 us; speedup vs baseline: 1.0956x; 1.0956x over previous
//
#include <hip/hip_runtime.h>

#define EPS 1e-5f

constexpr int FIN = 22;   // input feature dim
constexpr int XP  = 32;   // padded x feature stride
constexpr int H   = 128;  // hidden dim
constexpr int SLICE_SHIFT = 17;  // 131072 CSR entries (512KB) per slice
constexpr int EPB = 2048;        // edges per scatter block-chunk

// bf16 helpers (bit-level, RN-even)
static __device__ __forceinline__ unsigned short f2bf(float f) {
    unsigned int u = __float_as_uint(f);
    unsigned int r = (u + 0x7fffu + ((u >> 16) & 1u)) >> 16;
    return (unsigned short)r;
}
static __device__ __forceinline__ float bflo(unsigned int u) {  // low bf16 of a dword
    return __uint_as_float(u << 16);
}
static __device__ __forceinline__ float bfhi(unsigned int u) {  // high bf16 of a dword
    return __uint_as_float(u & 0xffff0000u);
}

// ---------------- degree + in-edge rank (one atomic pass); BN prep folded into block 0 ----------------
__global__ void rank_kernel(const int* __restrict__ ei, int* __restrict__ degi,
                            int* __restrict__ rank, int E,
                            const float* __restrict__ b1, const float* __restrict__ mean1,
                            const float* __restrict__ var1, const float* __restrict__ gamma1,
                            const float* __restrict__ beta1,
                            const float* __restrict__ b2, const float* __restrict__ mean2,
                            const float* __restrict__ var2, const float* __restrict__ gamma2,
                            const float* __restrict__ beta2,
                            float* __restrict__ A1f, float* __restrict__ B1f,
                            float* __restrict__ A2f, float* __restrict__ B2f) {
    int e = blockIdx.x * blockDim.x + threadIdx.x;
    if (e < E) rank[e] = atomicAdd(&degi[ei[E + e]], 1);
    if (blockIdx.x == 0 && threadIdx.x < H) {
        int t = threadIdx.x;
        float A1 = gamma1[t] * rsqrtf(var1[t] + EPS);
        A1f[t] = A1;
        B1f[t] = (b1[t] - mean1[t]) * A1 + beta1[t];
        float A2 = gamma2[t] * rsqrtf(var2[t] + EPS);
        A2f[t] = A2;
        B2f[t] = (b2[t] - mean2[t]) * A2 + beta2[t];
    }
}

// ---------------- scan phase A: per-block exclusive scan + dinv + xr = bf16(x*dinv) ----------------
__global__ __launch_bounds__(256) void scanA_kernel(
    const int* __restrict__ degi, const float* __restrict__ x,
    int* __restrict__ offs, int* __restrict__ bsum,
    float* __restrict__ dinv, unsigned short* __restrict__ xb, int N) {
    __shared__ int sh[256];
    const int t = threadIdx.x;
    const int i = blockIdx.x * 256 + t;
    int v = (i < N) ? degi[i] : 0;
    sh[t] = v;
    __syncthreads();
    int val = v;
    for (int off = 1; off < 256; off <<= 1) {
        int add = (t >= off) ? sh[t - off] : 0;
        __syncthreads();
        val += add;
        sh[t] = val;
        __syncthreads();
    }
    if (i < N) offs[i] = val - v;          // exclusive within block (global base added by consumers)
    if (t == 255) bsum[blockIdx.x] = val;  // block total
    if (i < N) {
        float di = rsqrtf((float)v + 1.0f); // +1 self-loop
        dinv[i] = di;
#pragma unroll
        for (int k = 0; k < XP; ++k)
            xb[i * XP + k] = (k < FIN) ? f2bf(x[i * FIN + k] * di) : (unsigned short)0;
    }
}

// ---------------- scan phase B: exclusive scan of block sums ----------------
__global__ __launch_bounds__(256) void scanB_kernel(int* __restrict__ bsum, int nb) {
    __shared__ int sh[256];
    const int t = threadIdx.x;
    int v = (t < nb) ? bsum[t] : 0;
    sh[t] = v;
    __syncthreads();
    int val = v;
    for (int off = 1; off < 256; off <<= 1) {
        int add = (t >= off) ? sh[t - off] : 0;
        __syncthreads();
        val += add;
        sh[t] = val;
        __syncthreads();
    }
    if (t < nb) bsum[t] = val - v;
}

// global CSR start of node i (i < N); use E for i == N
static __device__ __forceinline__ int off_at(const int* __restrict__ offs,
                                             const int* __restrict__ bsum,
                                             int i, int N, int E) {
    return (i < N) ? offs[i] + bsum[i >> 8] : E;
}

// ---------------- XCD-sliced CSR scatter ----------------
__global__ __launch_bounds__(256) void scatter8_kernel(
    const int* __restrict__ ei, const int* __restrict__ rank,
    const int* __restrict__ offs, const int* __restrict__ bsum,
    int* __restrict__ csrS, int E, int nslice) {
    const int r = blockIdx.x & 7;
    if (r >= nslice) return;
    const int chunk = blockIdx.x >> 3;
    const int e1 = min(chunk * EPB + EPB, E);
    for (int e = chunk * EPB + threadIdx.x; e < e1; e += 256) {
        int d = ei[E + e];
        int p = offs[d] + bsum[d >> 8] + rank[e];
        if ((p >> SLICE_SHIFT) == r) csrS[p] = ei[e];
    }
}
// CSR range of node d = [ off_at(d), off_at(d+1) )

// ---------------- fused: layer-1 gather + gemm1 + BN1 + ReLU + gemm2 (+A2*dinv -> bf16) --------
// Gather phase: 16-lane group per node; lane fl reads feats [2fl, 2fl+1] (one 64B line/edge/group).
// h1 tile stays in LDS (transposed, pad 20); h2 row written once, pre-scaled by A2*dinv.
__global__ __launch_bounds__(256) void gemm12f_kernel(
    const unsigned short* __restrict__ xb, const float* __restrict__ dinv,
    const int* __restrict__ offs, const int* __restrict__ bsum,
    const int* __restrict__ csrS,
    const float* __restrict__ W1, const float* __restrict__ W2,
    const float* __restrict__ A1f, const float* __restrict__ B1f,
    const float* __restrict__ A2f,
    unsigned short* __restrict__ h2b, int N, int E) {
    __shared__ float lds1[16 * XP];        // gathered xa tile
    __shared__ float lds2[H * 20];         // h1 tile, transposed [k][row], pad 20
    const int tid = threadIdx.x;
    const int m0  = blockIdx.x * 16;

    // ---- fused gather into lds1 ----
    {
        const int g    = tid >> 4;         // group 0..15 -> node m0+g
        const int fl   = tid & 15;         // lane in group: feats 2fl, 2fl+1
        const int node = m0 + g;
        if (node < N) {
            const int beg = off_at(offs, bsum, node, N, E);
            const int end = off_at(offs, bsum, node + 1, N, E);
            unsigned int v = *reinterpret_cast<const unsigned int*>(
                xb + (size_t)node * XP + fl * 2);
            float a0 = bflo(v), a1 = bfhi(v);   // self row (own dinv pre-folded)
            int e = beg;
            for (; e + 1 < end; e += 2) {
                int s0 = csrS[e], s1 = csrS[e + 1];
                unsigned int v0 = *reinterpret_cast<const unsigned int*>(
                    xb + (size_t)s0 * XP + fl * 2);
                unsigned int v1 = *reinterpret_cast<const unsigned int*>(
                    xb + (size_t)s1 * XP + fl * 2);
                a0 += bflo(v0) + bflo(v1);
                a1 += bfhi(v0) + bfhi(v1);
            }
            if (e < end) {
                int s = csrS[e];
                unsigned int v2 = *reinterpret_cast<const unsigned int*>(
                    xb + (size_t)s * XP + fl * 2);
                a0 += bflo(v2); a1 += bfhi(v2);
            }
            float di = dinv[node];
            lds1[g * XP + fl * 2]     = a0 * di;
            lds1[g * XP + fl * 2 + 1] = a1 * di;
        }
    }
    __syncthreads();

    const int f  = tid & 127;
    const int mg = tid >> 7;

    // gemm1
    float acc1[8];
#pragma unroll
    for (int j = 0; j < 8; ++j) acc1[j] = 0.0f;
    for (int k = 0; k < FIN; ++k) {
        float w = W1[k * H + f];
#pragma unroll
        for (int j = 0; j < 8; ++j) acc1[j] += lds1[(mg * 8 + j) * XP + k] * w;
    }
    const float A1 = A1f[f], B1 = B1f[f];
    float4 h1a, h1b;
    h1a.x = fmaxf(acc1[0] * A1 + B1, 0.f); h1a.y = fmaxf(acc1[1] * A1 + B1, 0.f);
    h1a.z = fmaxf(acc1[2] * A1 + B1, 0.f); h1a.w = fmaxf(acc1[3] * A1 + B1, 0.f);
    h1b.x = fmaxf(acc1[4] * A1 + B1, 0.f); h1b.y = fmaxf(acc1[5] * A1 + B1, 0.f);
    h1b.z = fmaxf(acc1[6] * A1 + B1, 0.f); h1b.w = fmaxf(acc1[7] * A1 + B1, 0.f);
    *reinterpret_cast<float4*>(&lds2[f * 20 + mg * 8])     = h1a;
    *reinterpret_cast<float4*>(&lds2[f * 20 + mg * 8 + 4]) = h1b;
    __syncthreads();

    // gemm2
    float acc2[8];
#pragma unroll
    for (int j = 0; j < 8; ++j) acc2[j] = 0.0f;
    for (int k = 0; k < H; ++k) {
        float w = W2[k * H + f];
        float4 ha = *reinterpret_cast<const float4*>(&lds2[k * 20 + mg * 8]);
        float4 hb = *reinterpret_cast<const float4*>(&lds2[k * 20 + mg * 8 + 4]);
        acc2[0] += ha.x * w; acc2[1] += ha.y * w; acc2[2] += ha.z * w; acc2[3] += ha.w * w;
        acc2[4] += hb.x * w; acc2[5] += hb.y * w; acc2[6] += hb.z * w; acc2[7] += hb.w * w;
    }
    const float A2 = A2f[f];
#pragma unroll
    for (int j = 0; j < 8; ++j) {
        int node = m0 + mg * 8 + j;
        if (node < N) {
            float sc = A2 * dinv[node];   // fold own dinv into stored row
            h2b[(size_t)node * H + f] = f2bf(acc2[j] * sc);
        }
    }
}

// ---------------- fused: layer-2 gather (pure row sum) + BN2 + ReLU + FC + sigmoid ----------------
// wave = 4 groups x 16 lanes; 2-row body (round-5 shape, best measured)
__global__ __launch_bounds__(256) void gfinal_kernel(
    const unsigned short* __restrict__ h2b, const float* __restrict__ dinv,
    const int* __restrict__ offs, const int* __restrict__ bsum,
    const int* __restrict__ csrS,
    const float* __restrict__ B2f, const float* __restrict__ Wfc,
    const float* __restrict__ bfc, float* __restrict__ out, int N, int E) {
    const int tid  = threadIdx.x;
    const int node = blockIdx.x * 4 + (tid >> 6);
    const int lane = tid & 63;
    if (node >= N) return;
    const int g  = lane >> 4;      // group 0..3
    const int fl = lane & 15;      // lane in group
    const int f0 = fl * 8;
    const int beg = off_at(offs, bsum, node, N, E);
    const int end = off_at(offs, bsum, node + 1, N, E);

    float acc[8];
#pragma unroll
    for (int j = 0; j < 8; ++j) acc[j] = 0.0f;

    if (g == 0) {  // self row, weight 1
        uint4 v = *reinterpret_cast<const uint4*>(h2b + (size_t)node * H + f0);
        acc[0] = bflo(v.x); acc[1] = bfhi(v.x);
        acc[2] = bflo(v.y); acc[3] = bfhi(v.y);
        acc[4] = bflo(v.z); acc[5] = bfhi(v.z);
        acc[6] = bflo(v.w); acc[7] = bfhi(v.w);
    }
    int e = beg + g;
    for (; e + 4 < end; e += 8) {
        int s0 = csrS[e];
        int s1 = csrS[e + 4];
        uint4 v0 = *reinterpret_cast<const uint4*>(h2b + (size_t)s0 * H + f0);
        uint4 v1 = *reinterpret_cast<const uint4*>(h2b + (size_t)s1 * H + f0);
        acc[0] += bflo(v0.x) + bflo(v1.x); acc[1] += bfhi(v0.x) + bfhi(v1.x);
        acc[2] += bflo(v0.y) + bflo(v1.y); acc[3] += bfhi(v0.y) + bfhi(v1.y);
        acc[4] += bflo(v0.z) + bflo(v1.z); acc[5] += bfhi(v0.z) + bfhi(v1.z);
        acc[6] += bflo(v0.w) + bflo(v1.w); acc[7] += bfhi(v0.w) + bfhi(v1.w);
    }
    if (e < end) {
        int s = csrS[e];
        uint4 v = *reinterpret_cast<const uint4*>(h2b + (size_t)s * H + f0);
        acc[0] += bflo(v.x); acc[1] += bfhi(v.x);
        acc[2] += bflo(v.y); acc[3] += bfhi(v.y);
        acc[4] += bflo(v.z); acc[5] += bfhi(v.z);
        acc[6] += bflo(v.w); acc[7] += bfhi(v.w);
    }
#pragma unroll
    for (int j = 0; j < 8; ++j) {
        acc[j] += __shfl_xor(acc[j], 16);
        acc[j] += __shfl_xor(acc[j], 32);
    }
    const float di = dinv[node];
    float p = 0.0f;
#pragma unroll
    for (int j = 0; j < 8; ++j)
        p += fmaxf(acc[j] * di + B2f[f0 + j], 0.0f) * Wfc[f0 + j];
#pragma unroll
    for (int off = 1; off < 16; off <<= 1) p += __shfl_xor(p, off);
    if (lane == 0) out[node] = 1.0f / (1.0f + expf(-(p + bfc[0])));
}

static inline size_t align4w(size_t w) { return (w + 3) & ~(size_t)3; }  // 16B align (words)

extern "C" void kernel_launch(void* const* d_in, const int* in_sizes, int n_in,
                              void* d_out, int out_size, void* d_ws, size_t ws_size,
                              hipStream_t stream) {
    const float* x      = (const float*)d_in[0];
    const int*   ei     = (const int*)d_in[1];
    const float* W1     = (const float*)d_in[2];
    const float* b1     = (const float*)d_in[3];
    const float* gamma1 = (const float*)d_in[4];
    const float* beta1  = (const float*)d_in[5];
    const float* mean1  = (const float*)d_in[6];
    const float* var1   = (const float*)d_in[7];
    const float* W2     = (const float*)d_in[8];
    const float* b2     = (const float*)d_in[9];
    const float* gamma2 = (const float*)d_in[10];
    const float* beta2  = (const float*)d_in[11];
    const float* mean2  = (const float*)d_in[12];
    const float* var2   = (const float*)d_in[13];
    const float* Wfc    = (const float*)d_in[14];
    const float* bfc    = (const float*)d_in[15];
    float* out = (float*)d_out;

    const int N = in_sizes[0] / FIN;   // 50000
    const int E = in_sizes[1] / 2;     // 800000
    const int NB = (N + 255) / 256;
    const int nslice = (E + (1 << SLICE_SHIFT) - 1) >> SLICE_SHIFT;  // 7 for E=800000

    // workspace layout (4-byte words, 16B-aligned sections)
    int* base = (int*)d_ws;
    size_t o = 0;
    int*   degi = base + o;                o = align4w(o + N);
    float* dinv = (float*)(base + o);      o = align4w(o + N);
    int*   offs = base + o;                o = align4w(o + N + 1);
    int*   bsum = base + o;                o = align4w(o + 256);
    float* A1f  = (float*)(base + o);      o = align4w(o + H);
    float* B1f  = (float*)(base + o);      o = align4w(o + H);
    float* A2f  = (float*)(base + o);      o = align4w(o + H);
    float* B2f  = (float*)(base + o);      o = align4w(o + H);
    int*   rank = base + o;                o = align4w(o + (size_t)E);
    int*   csrS = base + o;                o = align4w(o + (size_t)E);
    unsigned short* xb = (unsigned short*)(base + o); o = align4w(o + (size_t)N * XP / 2);
    unsigned short* h2b = (unsigned short*)(base + o);

    hipMemsetAsync(degi, 0, (size_t)N * sizeof(int), stream);

    rank_kernel<<<(E + 255) / 256, 256, 0, stream>>>(
        ei, degi, rank, E,
        b1, mean1, var1, gamma1, beta1, b2, mean2, var2, gamma2, beta2,
        A1f, B1f, A2f, B2f);
    scanA_kernel<<<NB, 256, 0, stream>>>(degi, x, offs, bsum, dinv, xb, N);
    scanB_kernel<<<1, 256, 0, stream>>>(bsum, NB);
    scatter8_kernel<<<((E + EPB - 1) / EPB) * 8, 256, 0, stream>>>(
        ei, rank, offs, bsum, csrS, E, nslice);

    gemm12f_kernel<<<(N + 15) / 16, 256, 0, stream>>>(
        xb, dinv, offs, bsum, csrS, W1, W2, A1f, B1f, A2f, h2b, N, E);
    gfinal_kernel<<<(N + 3) / 4, 256, 0, stream>>>(
        h2b, dinv, offs, bsum, csrS, B2f, Wfc, bfc, out, N, E);
}

// Round 9
// 161.450 us; speedup vs baseline: 1.2025x; 1.0976x over previous
//
#include <hip/hip_runtime.h>

#define EPS 1e-5f

constexpr int FIN = 22;   // input feature dim
constexpr int XP  = 32;   // padded x feature stride (= gemm1 K)
constexpr int H   = 128;  // hidden dim
constexpr int SLICE_SHIFT = 17;  // 131072 CSR entries (512KB) per slice
constexpr int EPB = 2048;        // edges per scatter block-chunk
constexpr int ALD = 136;         // LDS A-tile row stride (bf16 elems): 272B, 16B-aligned, 2-way banks

typedef __attribute__((ext_vector_type(8))) short bf16x8;   // 8 bf16 = 4 VGPRs
typedef __attribute__((ext_vector_type(4))) float f32x4;    // MFMA C/D

// bf16 helpers (bit-level, RN-even)
static __device__ __forceinline__ unsigned short f2bf(float f) {
    unsigned int u = __float_as_uint(f);
    unsigned int r = (u + 0x7fffu + ((u >> 16) & 1u)) >> 16;
    return (unsigned short)r;
}
static __device__ __forceinline__ float bf2f(unsigned short u) {
    return __uint_as_float(((unsigned int)u) << 16);
}
static __device__ __forceinline__ float bflo(unsigned int u) {
    return __uint_as_float(u << 16);
}
static __device__ __forceinline__ float bfhi(unsigned int u) {
    return __uint_as_float(u & 0xffff0000u);
}

// ---------------- rank (degree+rank atomic pass) + BN prep + W1/W2 fragment prep ----------------
// W fragment layout (per 16x16x32 MFMA): lane l supplies B[k=8*(l>>4)+j][col=l&15], j=0..7,
// packed j-pairs per dword. W2b idx = ((ct*4+ks)*64+lane); W1b idx = (ct*64+lane). hi/lo split.
__global__ void rank_kernel(const int* __restrict__ ei, int* __restrict__ degi,
                            int* __restrict__ rank, int E,
                            const float* __restrict__ b1, const float* __restrict__ mean1,
                            const float* __restrict__ var1, const float* __restrict__ gamma1,
                            const float* __restrict__ beta1,
                            const float* __restrict__ b2, const float* __restrict__ mean2,
                            const float* __restrict__ var2, const float* __restrict__ gamma2,
                            const float* __restrict__ beta2,
                            const float* __restrict__ W1, const float* __restrict__ W2,
                            float* __restrict__ A1f, float* __restrict__ B1f,
                            float* __restrict__ A2f, float* __restrict__ B2f,
                            unsigned int* __restrict__ W1bhi, unsigned int* __restrict__ W1blo,
                            unsigned int* __restrict__ W2bhi, unsigned int* __restrict__ W2blo) {
    int e = blockIdx.x * blockDim.x + threadIdx.x;
    if (e < E) rank[e] = atomicAdd(&degi[ei[E + e]], 1);

    if (blockIdx.x == 0 && threadIdx.x < H) {
        int t = threadIdx.x;
        float A1 = gamma1[t] * rsqrtf(var1[t] + EPS);
        A1f[t] = A1;
        B1f[t] = (b1[t] - mean1[t]) * A1 + beta1[t];
        float A2 = gamma2[t] * rsqrtf(var2[t] + EPS);
        A2f[t] = A2;
        B2f[t] = (b2[t] - mean2[t]) * A2 + beta2[t];
    } else if (blockIdx.x >= 1 && blockIdx.x <= 8) {
        // W2 fragments: 2048 fragment-lanes
        int t = (blockIdx.x - 1) * 256 + threadIdx.x;
        int lane = t & 63, ks = (t >> 6) & 3, ct = t >> 8;
        int c  = ct * 16 + (lane & 15);
        int kb = ks * 32 + ((lane >> 4) << 3);
        unsigned int hi[4], lo[4];
#pragma unroll
        for (int d = 0; d < 4; ++d) {
            float f0 = W2[(kb + 2 * d) * H + c];
            float f1 = W2[(kb + 2 * d + 1) * H + c];
            unsigned short h0 = f2bf(f0), h1 = f2bf(f1);
            unsigned short l0 = f2bf(f0 - bf2f(h0)), l1 = f2bf(f1 - bf2f(h1));
            hi[d] = (unsigned int)h0 | ((unsigned int)h1 << 16);
            lo[d] = (unsigned int)l0 | ((unsigned int)l1 << 16);
        }
        *reinterpret_cast<uint4*>(W2bhi + (size_t)t * 4) = make_uint4(hi[0], hi[1], hi[2], hi[3]);
        *reinterpret_cast<uint4*>(W2blo + (size_t)t * 4) = make_uint4(lo[0], lo[1], lo[2], lo[3]);
    } else if (blockIdx.x == 9 || blockIdx.x == 10) {
        // W1 fragments: 512 fragment-lanes (K=32, zero-padded past FIN)
        int t = (blockIdx.x - 9) * 256 + threadIdx.x;
        int lane = t & 63, ct = t >> 6;
        int c  = ct * 16 + (lane & 15);
        int kb = (lane >> 4) << 3;
        unsigned int hi[4], lo[4];
#pragma unroll
        for (int d = 0; d < 4; ++d) {
            int k0 = kb + 2 * d, k1 = kb + 2 * d + 1;
            float f0 = (k0 < FIN) ? W1[k0 * H + c] : 0.0f;
            float f1 = (k1 < FIN) ? W1[k1 * H + c] : 0.0f;
            unsigned short h0 = f2bf(f0), h1 = f2bf(f1);
            unsigned short l0 = f2bf(f0 - bf2f(h0)), l1 = f2bf(f1 - bf2f(h1));
            hi[d] = (unsigned int)h0 | ((unsigned int)h1 << 16);
            lo[d] = (unsigned int)l0 | ((unsigned int)l1 << 16);
        }
        *reinterpret_cast<uint4*>(W1bhi + (size_t)t * 4) = make_uint4(hi[0], hi[1], hi[2], hi[3]);
        *reinterpret_cast<uint4*>(W1blo + (size_t)t * 4) = make_uint4(lo[0], lo[1], lo[2], lo[3]);
    }
}

// ---------------- scan phase A: per-block exclusive scan + dinv + xr = bf16(x*dinv) ----------------
__global__ __launch_bounds__(256) void scanA_kernel(
    const int* __restrict__ degi, const float* __restrict__ x,
    int* __restrict__ offs, int* __restrict__ bsum,
    float* __restrict__ dinv, unsigned short* __restrict__ xb, int N) {
    __shared__ int sh[256];
    const int t = threadIdx.x;
    const int i = blockIdx.x * 256 + t;
    int v = (i < N) ? degi[i] : 0;
    sh[t] = v;
    __syncthreads();
    int val = v;
    for (int off = 1; off < 256; off <<= 1) {
        int add = (t >= off) ? sh[t - off] : 0;
        __syncthreads();
        val += add;
        sh[t] = val;
        __syncthreads();
    }
    if (i < N) offs[i] = val - v;          // exclusive within block (global base added by consumers)
    if (t == 255) bsum[blockIdx.x] = val;  // block total
    if (i < N) {
        float di = rsqrtf((float)v + 1.0f); // +1 self-loop
        dinv[i] = di;
#pragma unroll
        for (int k = 0; k < XP; ++k)
            xb[i * XP + k] = (k < FIN) ? f2bf(x[i * FIN + k] * di) : (unsigned short)0;
    }
}

// ---------------- scan phase B: exclusive scan of block sums ----------------
__global__ __launch_bounds__(256) void scanB_kernel(int* __restrict__ bsum, int nb) {
    __shared__ int sh[256];
    const int t = threadIdx.x;
    int v = (t < nb) ? bsum[t] : 0;
    sh[t] = v;
    __syncthreads();
    int val = v;
    for (int off = 1; off < 256; off <<= 1) {
        int add = (t >= off) ? sh[t - off] : 0;
        __syncthreads();
        val += add;
        sh[t] = val;
        __syncthreads();
    }
    if (t < nb) bsum[t] = val - v;
}

// global CSR start of node i (i < N); use E for i == N
static __device__ __forceinline__ int off_at(const int* __restrict__ offs,
                                             const int* __restrict__ bsum,
                                             int i, int N, int E) {
    return (i < N) ? offs[i] + bsum[i >> 8] : E;
}

// ---------------- XCD-sliced CSR scatter ----------------
__global__ __launch_bounds__(256) void scatter8_kernel(
    const int* __restrict__ ei, const int* __restrict__ rank,
    const int* __restrict__ offs, const int* __restrict__ bsum,
    int* __restrict__ csrS, int E, int nslice) {
    const int r = blockIdx.x & 7;
    if (r >= nslice) return;
    const int chunk = blockIdx.x >> 3;
    const int e1 = min(chunk * EPB + EPB, E);
    for (int e = chunk * EPB + threadIdx.x; e < e1; e += 256) {
        int d = ei[E + e];
        int p = offs[d] + bsum[d >> 8] + rank[e];
        if ((p >> SLICE_SHIFT) == r) csrS[p] = ei[e];
    }
}
// CSR range of node d = [ off_at(d), off_at(d+1) )

// ---------------- fused: gather + MFMA gemm1 + BN1 + ReLU + MFMA gemm2 -> h2b ----------------
// A-frag: lane l = row l&15, k = 8*(l>>4)+j. C/D: col = lane&15, row = (lane>>4)*4+reg (m89).
// hi/lo bf16 decomposition on both operands (3 MFMA/tile-step) keeps f32-grade accuracy.
__global__ __launch_bounds__(256) void gemm12f_kernel(
    const unsigned short* __restrict__ xb, const float* __restrict__ dinv,
    const int* __restrict__ offs, const int* __restrict__ bsum,
    const int* __restrict__ csrS,
    const unsigned int* __restrict__ W1bhi, const unsigned int* __restrict__ W1blo,
    const unsigned int* __restrict__ W2bhi, const unsigned int* __restrict__ W2blo,
    const float* __restrict__ A1f, const float* __restrict__ B1f,
    const float* __restrict__ A2f,
    unsigned short* __restrict__ h2b, int N, int E) {
    __shared__ __align__(16) unsigned short Ahi[16 * ALD];
    __shared__ __align__(16) unsigned short Alo[16 * ALD];
    __shared__ float dil[16];
    const int tid = threadIdx.x;
    const int m0  = blockIdx.x * 16;

    // ---- gather into A-layout bf16 hi/lo (gemm1 A: k = feature 0..31) ----
    {
        const int g = tid >> 4, fl = tid & 15;
        const int node = m0 + g;
        if (node < N) {
            const int beg = off_at(offs, bsum, node, N, E);
            const int end = off_at(offs, bsum, node + 1, N, E);
            unsigned int v = *reinterpret_cast<const unsigned int*>(
                xb + (size_t)node * XP + fl * 2);
            float a0 = bflo(v), a1 = bfhi(v);   // self row (own dinv pre-folded in xb)
            int e = beg;
            for (; e + 1 < end; e += 2) {
                int s0 = csrS[e], s1 = csrS[e + 1];
                unsigned int v0 = *reinterpret_cast<const unsigned int*>(
                    xb + (size_t)s0 * XP + fl * 2);
                unsigned int v1 = *reinterpret_cast<const unsigned int*>(
                    xb + (size_t)s1 * XP + fl * 2);
                a0 += bflo(v0) + bflo(v1);
                a1 += bfhi(v0) + bfhi(v1);
            }
            if (e < end) {
                int s = csrS[e];
                unsigned int v2 = *reinterpret_cast<const unsigned int*>(
                    xb + (size_t)s * XP + fl * 2);
                a0 += bflo(v2); a1 += bfhi(v2);
            }
            float di = dinv[node];
            if (fl == 0) dil[g] = di;
            a0 *= di; a1 *= di;
            unsigned short h0 = f2bf(a0), h1 = f2bf(a1);
            unsigned short l0 = f2bf(a0 - bf2f(h0)), l1 = f2bf(a1 - bf2f(h1));
            *reinterpret_cast<unsigned int*>(&Ahi[g * ALD + fl * 2]) =
                (unsigned int)h0 | ((unsigned int)h1 << 16);
            *reinterpret_cast<unsigned int*>(&Alo[g * ALD + fl * 2]) =
                (unsigned int)l0 | ((unsigned int)l1 << 16);
        }
    }
    __syncthreads();

    const int w    = tid >> 6;
    const int lane = tid & 63;
    const int arow = lane & 15;
    const int kgrp = lane >> 4;

    // ---- gemm1 MFMA (K=32, one step, 2 col-tiles/wave) ----
    f32x4 z = {0.f, 0.f, 0.f, 0.f};
    f32x4 acc1[2] = {z, z};
    {
        bf16x8 ah = *reinterpret_cast<const bf16x8*>(&Ahi[arow * ALD + kgrp * 8]);
        bf16x8 al = *reinterpret_cast<const bf16x8*>(&Alo[arow * ALD + kgrp * 8]);
#pragma unroll
        for (int t = 0; t < 2; ++t) {
            int idx = (w * 2 + t) * 64 + lane;
            bf16x8 bh = *reinterpret_cast<const bf16x8*>(W1bhi + (size_t)idx * 4);
            bf16x8 bl = *reinterpret_cast<const bf16x8*>(W1blo + (size_t)idx * 4);
            acc1[t] = __builtin_amdgcn_mfma_f32_16x16x32_bf16(ah, bh, acc1[t], 0, 0, 0);
            acc1[t] = __builtin_amdgcn_mfma_f32_16x16x32_bf16(ah, bl, acc1[t], 0, 0, 0);
            acc1[t] = __builtin_amdgcn_mfma_f32_16x16x32_bf16(al, bh, acc1[t], 0, 0, 0);
        }
    }
    __syncthreads();   // all gemm1 A-reads done before overwrite

    // ---- epilogue-1: BN1+ReLU, hi/lo split, write back as gemm2's A (k = feature 0..127) ----
#pragma unroll
    for (int t = 0; t < 2; ++t) {
        int col = (w * 2 + t) * 16 + arow;
        float a1c = A1f[col], b1c = B1f[col];
#pragma unroll
        for (int r = 0; r < 4; ++r) {
            int row = kgrp * 4 + r;
            float h = fmaxf(acc1[t][r] * a1c + b1c, 0.f);
            unsigned short hh = f2bf(h);
            unsigned short hl = f2bf(h - bf2f(hh));
            Ahi[row * ALD + col] = hh;
            Alo[row * ALD + col] = hl;
        }
    }
    __syncthreads();

    // ---- gemm2 MFMA (K=128, 4 steps, 2 col-tiles/wave) ----
    f32x4 acc2[2] = {z, z};
    for (int ks = 0; ks < 4; ++ks) {
        bf16x8 ah = *reinterpret_cast<const bf16x8*>(&Ahi[arow * ALD + ks * 32 + kgrp * 8]);
        bf16x8 al = *reinterpret_cast<const bf16x8*>(&Alo[arow * ALD + ks * 32 + kgrp * 8]);
#pragma unroll
        for (int t = 0; t < 2; ++t) {
            int idx = ((w * 2 + t) * 4 + ks) * 64 + lane;
            bf16x8 bh = *reinterpret_cast<const bf16x8*>(W2bhi + (size_t)idx * 4);
            bf16x8 bl = *reinterpret_cast<const bf16x8*>(W2blo + (size_t)idx * 4);
            acc2[t] = __builtin_amdgcn_mfma_f32_16x16x32_bf16(ah, bh, acc2[t], 0, 0, 0);
            acc2[t] = __builtin_amdgcn_mfma_f32_16x16x32_bf16(ah, bl, acc2[t], 0, 0, 0);
            acc2[t] = __builtin_amdgcn_mfma_f32_16x16x32_bf16(al, bh, acc2[t], 0, 0, 0);
        }
    }

    // ---- epilogue-2: h2b = bf16(acc2 * A2[col] * dinv[node]) ----
#pragma unroll
    for (int t = 0; t < 2; ++t) {
        int col = (w * 2 + t) * 16 + arow;
        float sc = A2f[col];
#pragma unroll
        for (int r = 0; r < 4; ++r) {
            int row = kgrp * 4 + r;
            int node = m0 + row;
            if (node < N)
                h2b[(size_t)node * H + col] = f2bf(acc2[t][r] * sc * dil[row]);
        }
    }
}

// ---------------- fused: layer-2 gather (pure row sum) + BN2 + ReLU + FC + sigmoid ----------------
// wave = 4 groups x 16 lanes; 2-row body (round-5 shape, best measured)
__global__ __launch_bounds__(256) void gfinal_kernel(
    const unsigned short* __restrict__ h2b, const float* __restrict__ dinv,
    const int* __restrict__ offs, const int* __restrict__ bsum,
    const int* __restrict__ csrS,
    const float* __restrict__ B2f, const float* __restrict__ Wfc,
    const float* __restrict__ bfc, float* __restrict__ out, int N, int E) {
    const int tid  = threadIdx.x;
    const int node = blockIdx.x * 4 + (tid >> 6);
    const int lane = tid & 63;
    if (node >= N) return;
    const int g  = lane >> 4;      // group 0..3
    const int fl = lane & 15;      // lane in group
    const int f0 = fl * 8;
    const int beg = off_at(offs, bsum, node, N, E);
    const int end = off_at(offs, bsum, node + 1, N, E);

    float acc[8];
#pragma unroll
    for (int j = 0; j < 8; ++j) acc[j] = 0.0f;

    if (g == 0) {  // self row, weight 1
        uint4 v = *reinterpret_cast<const uint4*>(h2b + (size_t)node * H + f0);
        acc[0] = bflo(v.x); acc[1] = bfhi(v.x);
        acc[2] = bflo(v.y); acc[3] = bfhi(v.y);
        acc[4] = bflo(v.z); acc[5] = bfhi(v.z);
        acc[6] = bflo(v.w); acc[7] = bfhi(v.w);
    }
    int e = beg + g;
    for (; e + 4 < end; e += 8) {
        int s0 = csrS[e];
        int s1 = csrS[e + 4];
        uint4 v0 = *reinterpret_cast<const uint4*>(h2b + (size_t)s0 * H + f0);
        uint4 v1 = *reinterpret_cast<const uint4*>(h2b + (size_t)s1 * H + f0);
        acc[0] += bflo(v0.x) + bflo(v1.x); acc[1] += bfhi(v0.x) + bfhi(v1.x);
        acc[2] += bflo(v0.y) + bflo(v1.y); acc[3] += bfhi(v0.y) + bfhi(v1.y);
        acc[4] += bflo(v0.z) + bflo(v1.z); acc[5] += bfhi(v0.z) + bfhi(v1.z);
        acc[6] += bflo(v0.w) + bflo(v1.w); acc[7] += bfhi(v0.w) + bfhi(v1.w);
    }
    if (e < end) {
        int s = csrS[e];
        uint4 v = *reinterpret_cast<const uint4*>(h2b + (size_t)s * H + f0);
        acc[0] += bflo(v.x); acc[1] += bfhi(v.x);
        acc[2] += bflo(v.y); acc[3] += bfhi(v.y);
        acc[4] += bflo(v.z); acc[5] += bfhi(v.z);
        acc[6] += bflo(v.w); acc[7] += bfhi(v.w);
    }
#pragma unroll
    for (int j = 0; j < 8; ++j) {
        acc[j] += __shfl_xor(acc[j], 16);
        acc[j] += __shfl_xor(acc[j], 32);
    }
    const float di = dinv[node];
    float p = 0.0f;
#pragma unroll
    for (int j = 0; j < 8; ++j)
        p += fmaxf(acc[j] * di + B2f[f0 + j], 0.0f) * Wfc[f0 + j];
#pragma unroll
    for (int off = 1; off < 16; off <<= 1) p += __shfl_xor(p, off);
    if (lane == 0) out[node] = 1.0f / (1.0f + expf(-(p + bfc[0])));
}

static inline size_t align4w(size_t w) { return (w + 3) & ~(size_t)3; }  // 16B align (words)

extern "C" void kernel_launch(void* const* d_in, const int* in_sizes, int n_in,
                              void* d_out, int out_size, void* d_ws, size_t ws_size,
                              hipStream_t stream) {
    const float* x      = (const float*)d_in[0];
    const int*   ei     = (const int*)d_in[1];
    const float* W1     = (const float*)d_in[2];
    const float* b1     = (const float*)d_in[3];
    const float* gamma1 = (const float*)d_in[4];
    const float* beta1  = (const float*)d_in[5];
    const float* mean1  = (const float*)d_in[6];
    const float* var1   = (const float*)d_in[7];
    const float* W2     = (const float*)d_in[8];
    const float* b2     = (const float*)d_in[9];
    const float* gamma2 = (const float*)d_in[10];
    const float* beta2  = (const float*)d_in[11];
    const float* mean2  = (const float*)d_in[12];
    const float* var2   = (const float*)d_in[13];
    const float* Wfc    = (const float*)d_in[14];
    const float* bfc    = (const float*)d_in[15];
    float* out = (float*)d_out;

    const int N = in_sizes[0] / FIN;   // 50000
    const int E = in_sizes[1] / 2;     // 800000
    const int NB = (N + 255) / 256;
    const int nslice = (E + (1 << SLICE_SHIFT) - 1) >> SLICE_SHIFT;  // 7 for E=800000

    // workspace layout (4-byte words, 16B-aligned sections)
    int* base = (int*)d_ws;
    size_t o = 0;
    int*   degi = base + o;                o = align4w(o + N);
    float* dinv = (float*)(base + o);      o = align4w(o + N);
    int*   offs = base + o;                o = align4w(o + N + 1);
    int*   bsum = base + o;                o = align4w(o + 256);
    float* A1f  = (float*)(base + o);      o = align4w(o + H);
    float* B1f  = (float*)(base + o);      o = align4w(o + H);
    float* A2f  = (float*)(base + o);      o = align4w(o + H);
    float* B2f  = (float*)(base + o);      o = align4w(o + H);
    unsigned int* W1bhi = (unsigned int*)(base + o); o = align4w(o + 2048);
    unsigned int* W1blo = (unsigned int*)(base + o); o = align4w(o + 2048);
    unsigned int* W2bhi = (unsigned int*)(base + o); o = align4w(o + 8192);
    unsigned int* W2blo = (unsigned int*)(base + o); o = align4w(o + 8192);
    int*   rank = base + o;                o = align4w(o + (size_t)E);
    int*   csrS = base + o;                o = align4w(o + (size_t)E);
    unsigned short* xb = (unsigned short*)(base + o); o = align4w(o + (size_t)N * XP / 2);
    unsigned short* h2b = (unsigned short*)(base + o);

    hipMemsetAsync(degi, 0, (size_t)N * sizeof(int), stream);

    rank_kernel<<<(E + 255) / 256, 256, 0, stream>>>(
        ei, degi, rank, E,
        b1, mean1, var1, gamma1, beta1, b2, mean2, var2, gamma2, beta2,
        W1, W2, A1f, B1f, A2f, B2f, W1bhi, W1blo, W2bhi, W2blo);
    scanA_kernel<<<NB, 256, 0, stream>>>(degi, x, offs, bsum, dinv, xb, N);
    scanB_kernel<<<1, 256, 0, stream>>>(bsum, NB);
    scatter8_kernel<<<((E + EPB - 1) / EPB) * 8, 256, 0, stream>>>(
        ei, rank, offs, bsum, csrS, E, nslice);

    gemm12f_kernel<<<(N + 15) / 16, 256, 0, stream>>>(
        xb, dinv, offs, bsum, csrS, W1bhi, W1blo, W2bhi, W2blo,
        A1f, B1f, A2f, h2b, N, E);
    gfinal_kernel<<<(N + 3) / 4, 256, 0, stream>>>(
        h2b, dinv, offs, bsum, csrS, B2f, Wfc, bfc, out, N, E);
}

// Round 10
// 161.395 us; speedup vs baseline: 1.2029x; 1.0003x over previous
//
#include <hip/hip_runtime.h>

#define EPS 1e-5f

constexpr int FIN = 22;   // input feature dim
constexpr int XP  = 32;   // padded x feature stride (= gemm1 K)
constexpr int H   = 128;  // hidden dim
constexpr int SLICE_SHIFT = 17;  // 131072 CSR entries (512KB) per slice
constexpr int EPB = 2048;        // edges per scatter block-chunk
constexpr int ALD = 136;         // LDS A-tile row stride (bf16 elems): 272B, 16B-aligned, 2-way banks

typedef __attribute__((ext_vector_type(8))) short bf16x8;   // 8 bf16 = 4 VGPRs
typedef __attribute__((ext_vector_type(4))) float f32x4;    // MFMA C/D

// bf16 helpers (bit-level, RN-even)
static __device__ __forceinline__ unsigned short f2bf(float f) {
    unsigned int u = __float_as_uint(f);
    unsigned int r = (u + 0x7fffu + ((u >> 16) & 1u)) >> 16;
    return (unsigned short)r;
}
static __device__ __forceinline__ float bf2f(unsigned short u) {
    return __uint_as_float(((unsigned int)u) << 16);
}
static __device__ __forceinline__ float bflo(unsigned int u) {
    return __uint_as_float(u << 16);
}
static __device__ __forceinline__ float bfhi(unsigned int u) {
    return __uint_as_float(u & 0xffff0000u);
}

// ---------------- zero degi + scan counter (replaces 44us runtime fillBuffer) ----------------
__global__ void zero_kernel(int* __restrict__ p, int n) {
    int i = blockIdx.x * blockDim.x + threadIdx.x;
    if (i < n) p[i] = 0;
}

// ---------------- rank (degree+rank atomic pass) + BN prep + W1/W2 fragment prep ----------------
// W fragment layout (per 16x16x32 MFMA): lane l supplies B[k=8*(l>>4)+j][col=l&15], j=0..7,
// packed j-pairs per dword. W2b idx = ((ct*4+ks)*64+lane); W1b idx = (ct*64+lane). hi/lo split.
__global__ void rank_kernel(const int* __restrict__ ei, int* __restrict__ degi,
                            int* __restrict__ rank, int E,
                            const float* __restrict__ b1, const float* __restrict__ mean1,
                            const float* __restrict__ var1, const float* __restrict__ gamma1,
                            const float* __restrict__ beta1,
                            const float* __restrict__ b2, const float* __restrict__ mean2,
                            const float* __restrict__ var2, const float* __restrict__ gamma2,
                            const float* __restrict__ beta2,
                            const float* __restrict__ W1, const float* __restrict__ W2,
                            float* __restrict__ A1f, float* __restrict__ B1f,
                            float* __restrict__ A2f, float* __restrict__ B2f,
                            unsigned int* __restrict__ W1bhi, unsigned int* __restrict__ W1blo,
                            unsigned int* __restrict__ W2bhi, unsigned int* __restrict__ W2blo) {
    int e = blockIdx.x * blockDim.x + threadIdx.x;
    if (e < E) rank[e] = atomicAdd(&degi[ei[E + e]], 1);

    if (blockIdx.x == 0 && threadIdx.x < H) {
        int t = threadIdx.x;
        float A1 = gamma1[t] * rsqrtf(var1[t] + EPS);
        A1f[t] = A1;
        B1f[t] = (b1[t] - mean1[t]) * A1 + beta1[t];
        float A2 = gamma2[t] * rsqrtf(var2[t] + EPS);
        A2f[t] = A2;
        B2f[t] = (b2[t] - mean2[t]) * A2 + beta2[t];
    } else if (blockIdx.x >= 1 && blockIdx.x <= 8) {
        // W2 fragments: 2048 fragment-lanes
        int t = (blockIdx.x - 1) * 256 + threadIdx.x;
        int lane = t & 63, ks = (t >> 6) & 3, ct = t >> 8;
        int c  = ct * 16 + (lane & 15);
        int kb = ks * 32 + ((lane >> 4) << 3);
        unsigned int hi[4], lo[4];
#pragma unroll
        for (int d = 0; d < 4; ++d) {
            float f0 = W2[(kb + 2 * d) * H + c];
            float f1 = W2[(kb + 2 * d + 1) * H + c];
            unsigned short h0 = f2bf(f0), h1 = f2bf(f1);
            unsigned short l0 = f2bf(f0 - bf2f(h0)), l1 = f2bf(f1 - bf2f(h1));
            hi[d] = (unsigned int)h0 | ((unsigned int)h1 << 16);
            lo[d] = (unsigned int)l0 | ((unsigned int)l1 << 16);
        }
        *reinterpret_cast<uint4*>(W2bhi + (size_t)t * 4) = make_uint4(hi[0], hi[1], hi[2], hi[3]);
        *reinterpret_cast<uint4*>(W2blo + (size_t)t * 4) = make_uint4(lo[0], lo[1], lo[2], lo[3]);
    } else if (blockIdx.x == 9 || blockIdx.x == 10) {
        // W1 fragments: 512 fragment-lanes (K=32, zero-padded past FIN)
        int t = (blockIdx.x - 9) * 256 + threadIdx.x;
        int lane = t & 63, ct = t >> 6;
        int c  = ct * 16 + (lane & 15);
        int kb = (lane >> 4) << 3;
        unsigned int hi[4], lo[4];
#pragma unroll
        for (int d = 0; d < 4; ++d) {
            int k0 = kb + 2 * d, k1 = kb + 2 * d + 1;
            float f0 = (k0 < FIN) ? W1[k0 * H + c] : 0.0f;
            float f1 = (k1 < FIN) ? W1[k1 * H + c] : 0.0f;
            unsigned short h0 = f2bf(f0), h1 = f2bf(f1);
            unsigned short l0 = f2bf(f0 - bf2f(h0)), l1 = f2bf(f1 - bf2f(h1));
            hi[d] = (unsigned int)h0 | ((unsigned int)h1 << 16);
            lo[d] = (unsigned int)l0 | ((unsigned int)l1 << 16);
        }
        *reinterpret_cast<uint4*>(W1bhi + (size_t)t * 4) = make_uint4(hi[0], hi[1], hi[2], hi[3]);
        *reinterpret_cast<uint4*>(W1blo + (size_t)t * 4) = make_uint4(lo[0], lo[1], lo[2], lo[3]);
    }
}

// ---------------- scanA: per-block exclusive scan + dinv + xb=bf16(x*dinv); last block scans bsum ----
__global__ __launch_bounds__(256) void scanA_kernel(
    const int* __restrict__ degi, const float* __restrict__ x,
    int* __restrict__ offs, int* __restrict__ bsum, int* __restrict__ cnt,
    float* __restrict__ dinv, unsigned short* __restrict__ xb, int N) {
    __shared__ int sh[256];
    __shared__ int lastFlag;
    const int t = threadIdx.x;
    const int i = blockIdx.x * 256 + t;
    int v = (i < N) ? degi[i] : 0;
    sh[t] = v;
    __syncthreads();
    int val = v;
    for (int off = 1; off < 256; off <<= 1) {
        int add = (t >= off) ? sh[t - off] : 0;
        __syncthreads();
        val += add;
        sh[t] = val;
        __syncthreads();
    }
    if (i < N) offs[i] = val - v;          // exclusive within block (global base added by consumers)
    if (t == 255) bsum[blockIdx.x] = val;  // block total
    __syncthreads();                       // bsum store done block-wide
    if (t == 0) {
        __threadfence();                   // publish bsum before counting
        int c = atomicAdd(cnt, 1);
        lastFlag = (c == (int)gridDim.x - 1);
    }

    if (i < N) {
        float di = rsqrtf((float)v + 1.0f); // +1 self-loop
        dinv[i] = di;
#pragma unroll
        for (int k = 0; k < XP; ++k)
            xb[i * XP + k] = (k < FIN) ? f2bf(x[i * FIN + k] * di) : (unsigned short)0;
    }
    __syncthreads();

    if (lastFlag) {                        // merged scanB: exclusive scan of bsum
        const int nb = gridDim.x;
        int v2 = (t < nb) ? atomicAdd(&bsum[t], 0) : 0;  // device-scope read
        sh[t] = v2;
        __syncthreads();
        int val2 = v2;
        for (int off = 1; off < 256; off <<= 1) {
            int add = (t >= off) ? sh[t - off] : 0;
            __syncthreads();
            val2 += add;
            sh[t] = val2;
            __syncthreads();
        }
        if (t < nb) bsum[t] = val2 - v2;
    }
}

// global CSR start of node i (i < N); use E for i == N
static __device__ __forceinline__ int off_at(const int* __restrict__ offs,
                                             const int* __restrict__ bsum,
                                             int i, int N, int E) {
    return (i < N) ? offs[i] + bsum[i >> 8] : E;
}

// ---------------- XCD-sliced CSR scatter ----------------
__global__ __launch_bounds__(256) void scatter8_kernel(
    const int* __restrict__ ei, const int* __restrict__ rank,
    const int* __restrict__ offs, const int* __restrict__ bsum,
    int* __restrict__ csrS, int E, int nslice) {
    const int r = blockIdx.x & 7;
    if (r >= nslice) return;
    const int chunk = blockIdx.x >> 3;
    const int e1 = min(chunk * EPB + EPB, E);
    for (int e = chunk * EPB + threadIdx.x; e < e1; e += 256) {
        int d = ei[E + e];
        int p = offs[d] + bsum[d >> 8] + rank[e];
        if ((p >> SLICE_SHIFT) == r) csrS[p] = ei[e];
    }
}
// CSR range of node d = [ off_at(d), off_at(d+1) )

// ---------------- fused: gather + MFMA gemm1 + BN1 + ReLU + MFMA gemm2 -> h2b ----------------
// A-frag: lane l = row l&15, k = 8*(l>>4)+j. C/D: col = lane&15, row = (lane>>4)*4+reg (m89).
// hi/lo bf16 decomposition on both operands (3 MFMA/tile-step) keeps f32-grade accuracy.
__global__ __launch_bounds__(256) void gemm12f_kernel(
    const unsigned short* __restrict__ xb, const float* __restrict__ dinv,
    const int* __restrict__ offs, const int* __restrict__ bsum,
    const int* __restrict__ csrS,
    const unsigned int* __restrict__ W1bhi, const unsigned int* __restrict__ W1blo,
    const unsigned int* __restrict__ W2bhi, const unsigned int* __restrict__ W2blo,
    const float* __restrict__ A1f, const float* __restrict__ B1f,
    const float* __restrict__ A2f,
    unsigned short* __restrict__ h2b, int N, int E) {
    __shared__ __align__(16) unsigned short Ahi[16 * ALD];
    __shared__ __align__(16) unsigned short Alo[16 * ALD];
    __shared__ float dil[16];
    const int tid = threadIdx.x;
    const int m0  = blockIdx.x * 16;

    // ---- gather into A-layout bf16 hi/lo (gemm1 A: k = feature 0..31), 4 loads in flight ----
    {
        const int g = tid >> 4, fl = tid & 15;
        const int node = m0 + g;
        if (node < N) {
            const int beg = off_at(offs, bsum, node, N, E);
            const int end = off_at(offs, bsum, node + 1, N, E);
            unsigned int v = *reinterpret_cast<const unsigned int*>(
                xb + (size_t)node * XP + fl * 2);
            float a0 = bflo(v), a1 = bfhi(v);   // self row (own dinv pre-folded in xb)
            int e = beg;
            for (; e + 3 < end; e += 4) {
                int s0 = csrS[e], s1 = csrS[e + 1], s2 = csrS[e + 2], s3 = csrS[e + 3];
                unsigned int v0 = *reinterpret_cast<const unsigned int*>(
                    xb + (size_t)s0 * XP + fl * 2);
                unsigned int v1 = *reinterpret_cast<const unsigned int*>(
                    xb + (size_t)s1 * XP + fl * 2);
                unsigned int v2 = *reinterpret_cast<const unsigned int*>(
                    xb + (size_t)s2 * XP + fl * 2);
                unsigned int v3 = *reinterpret_cast<const unsigned int*>(
                    xb + (size_t)s3 * XP + fl * 2);
                a0 += (bflo(v0) + bflo(v1)) + (bflo(v2) + bflo(v3));
                a1 += (bfhi(v0) + bfhi(v1)) + (bfhi(v2) + bfhi(v3));
            }
            for (; e < end; ++e) {
                int s = csrS[e];
                unsigned int v2 = *reinterpret_cast<const unsigned int*>(
                    xb + (size_t)s * XP + fl * 2);
                a0 += bflo(v2); a1 += bfhi(v2);
            }
            float di = dinv[node];
            if (fl == 0) dil[g] = di;
            a0 *= di; a1 *= di;
            unsigned short h0 = f2bf(a0), h1 = f2bf(a1);
            unsigned short l0 = f2bf(a0 - bf2f(h0)), l1 = f2bf(a1 - bf2f(h1));
            *reinterpret_cast<unsigned int*>(&Ahi[g * ALD + fl * 2]) =
                (unsigned int)h0 | ((unsigned int)h1 << 16);
            *reinterpret_cast<unsigned int*>(&Alo[g * ALD + fl * 2]) =
                (unsigned int)l0 | ((unsigned int)l1 << 16);
        }
    }
    __syncthreads();

    const int w    = tid >> 6;
    const int lane = tid & 63;
    const int arow = lane & 15;
    const int kgrp = lane >> 4;

    // ---- gemm1 MFMA (K=32, one step, 2 col-tiles/wave) ----
    f32x4 z = {0.f, 0.f, 0.f, 0.f};
    f32x4 acc1[2] = {z, z};
    {
        bf16x8 ah = *reinterpret_cast<const bf16x8*>(&Ahi[arow * ALD + kgrp * 8]);
        bf16x8 al = *reinterpret_cast<const bf16x8*>(&Alo[arow * ALD + kgrp * 8]);
#pragma unroll
        for (int t = 0; t < 2; ++t) {
            int idx = (w * 2 + t) * 64 + lane;
            bf16x8 bh = *reinterpret_cast<const bf16x8*>(W1bhi + (size_t)idx * 4);
            bf16x8 bl = *reinterpret_cast<const bf16x8*>(W1blo + (size_t)idx * 4);
            acc1[t] = __builtin_amdgcn_mfma_f32_16x16x32_bf16(ah, bh, acc1[t], 0, 0, 0);
            acc1[t] = __builtin_amdgcn_mfma_f32_16x16x32_bf16(ah, bl, acc1[t], 0, 0, 0);
            acc1[t] = __builtin_amdgcn_mfma_f32_16x16x32_bf16(al, bh, acc1[t], 0, 0, 0);
        }
    }
    __syncthreads();   // all gemm1 A-reads done before overwrite

    // ---- epilogue-1: BN1+ReLU, hi/lo split, write back as gemm2's A (k = feature 0..127) ----
#pragma unroll
    for (int t = 0; t < 2; ++t) {
        int col = (w * 2 + t) * 16 + arow;
        float a1c = A1f[col], b1c = B1f[col];
#pragma unroll
        for (int r = 0; r < 4; ++r) {
            int row = kgrp * 4 + r;
            float h = fmaxf(acc1[t][r] * a1c + b1c, 0.f);
            unsigned short hh = f2bf(h);
            unsigned short hl = f2bf(h - bf2f(hh));
            Ahi[row * ALD + col] = hh;
            Alo[row * ALD + col] = hl;
        }
    }
    __syncthreads();

    // ---- gemm2 MFMA (K=128, 4 steps, 2 col-tiles/wave) ----
    f32x4 acc2[2] = {z, z};
    for (int ks = 0; ks < 4; ++ks) {
        bf16x8 ah = *reinterpret_cast<const bf16x8*>(&Ahi[arow * ALD + ks * 32 + kgrp * 8]);
        bf16x8 al = *reinterpret_cast<const bf16x8*>(&Alo[arow * ALD + ks * 32 + kgrp * 8]);
#pragma unroll
        for (int t = 0; t < 2; ++t) {
            int idx = ((w * 2 + t) * 4 + ks) * 64 + lane;
            bf16x8 bh = *reinterpret_cast<const bf16x8*>(W2bhi + (size_t)idx * 4);
            bf16x8 bl = *reinterpret_cast<const bf16x8*>(W2blo + (size_t)idx * 4);
            acc2[t] = __builtin_amdgcn_mfma_f32_16x16x32_bf16(ah, bh, acc2[t], 0, 0, 0);
            acc2[t] = __builtin_amdgcn_mfma_f32_16x16x32_bf16(ah, bl, acc2[t], 0, 0, 0);
            acc2[t] = __builtin_amdgcn_mfma_f32_16x16x32_bf16(al, bh, acc2[t], 0, 0, 0);
        }
    }

    // ---- epilogue-2: h2b = bf16(acc2 * A2[col] * dinv[node]) ----
#pragma unroll
    for (int t = 0; t < 2; ++t) {
        int col = (w * 2 + t) * 16 + arow;
        float sc = A2f[col];
#pragma unroll
        for (int r = 0; r < 4; ++r) {
            int row = kgrp * 4 + r;
            int node = m0 + row;
            if (node < N)
                h2b[(size_t)node * H + col] = f2bf(acc2[t][r] * sc * dil[row]);
        }
    }
}

// ---------------- fused: layer-2 gather (pure row sum) + BN2 + ReLU + FC + sigmoid ----------------
// wave = 4 groups x 16 lanes; 2-row body (round-5 shape, best measured)
__global__ __launch_bounds__(256) void gfinal_kernel(
    const unsigned short* __restrict__ h2b, const float* __restrict__ dinv,
    const int* __restrict__ offs, const int* __restrict__ bsum,
    const int* __restrict__ csrS,
    const float* __restrict__ B2f, const float* __restrict__ Wfc,
    const float* __restrict__ bfc, float* __restrict__ out, int N, int E) {
    const int tid  = threadIdx.x;
    const int node = blockIdx.x * 4 + (tid >> 6);
    const int lane = tid & 63;
    if (node >= N) return;
    const int g  = lane >> 4;      // group 0..3
    const int fl = lane & 15;      // lane in group
    const int f0 = fl * 8;
    const int beg = off_at(offs, bsum, node, N, E);
    const int end = off_at(offs, bsum, node + 1, N, E);

    float acc[8];
#pragma unroll
    for (int j = 0; j < 8; ++j) acc[j] = 0.0f;

    if (g == 0) {  // self row, weight 1
        uint4 v = *reinterpret_cast<const uint4*>(h2b + (size_t)node * H + f0);
        acc[0] = bflo(v.x); acc[1] = bfhi(v.x);
        acc[2] = bflo(v.y); acc[3] = bfhi(v.y);
        acc[4] = bflo(v.z); acc[5] = bfhi(v.z);
        acc[6] = bflo(v.w); acc[7] = bfhi(v.w);
    }
    int e = beg + g;
    for (; e + 4 < end; e += 8) {
        int s0 = csrS[e];
        int s1 = csrS[e + 4];
        uint4 v0 = *reinterpret_cast<const uint4*>(h2b + (size_t)s0 * H + f0);
        uint4 v1 = *reinterpret_cast<const uint4*>(h2b + (size_t)s1 * H + f0);
        acc[0] += bflo(v0.x) + bflo(v1.x); acc[1] += bfhi(v0.x) + bfhi(v1.x);
        acc[2] += bflo(v0.y) + bflo(v1.y); acc[3] += bfhi(v0.y) + bfhi(v1.y);
        acc[4] += bflo(v0.z) + bflo(v1.z); acc[5] += bfhi(v0.z) + bfhi(v1.z);
        acc[6] += bflo(v0.w) + bflo(v1.w); acc[7] += bfhi(v0.w) + bfhi(v1.w);
    }
    if (e < end) {
        int s = csrS[e];
        uint4 v = *reinterpret_cast<const uint4*>(h2b + (size_t)s * H + f0);
        acc[0] += bflo(v.x); acc[1] += bfhi(v.x);
        acc[2] += bflo(v.y); acc[3] += bfhi(v.y);
        acc[4] += bflo(v.z); acc[5] += bfhi(v.z);
        acc[6] += bflo(v.w); acc[7] += bfhi(v.w);
    }
#pragma unroll
    for (int j = 0; j < 8; ++j) {
        acc[j] += __shfl_xor(acc[j], 16);
        acc[j] += __shfl_xor(acc[j], 32);
    }
    const float di = dinv[node];
    float p = 0.0f;
#pragma unroll
    for (int j = 0; j < 8; ++j)
        p += fmaxf(acc[j] * di + B2f[f0 + j], 0.0f) * Wfc[f0 + j];
#pragma unroll
    for (int off = 1; off < 16; off <<= 1) p += __shfl_xor(p, off);
    if (lane == 0) out[node] = 1.0f / (1.0f + expf(-(p + bfc[0])));
}

static inline size_t align4w(size_t w) { return (w + 3) & ~(size_t)3; }  // 16B align (words)

extern "C" void kernel_launch(void* const* d_in, const int* in_sizes, int n_in,
                              void* d_out, int out_size, void* d_ws, size_t ws_size,
                              hipStream_t stream) {
    const float* x      = (const float*)d_in[0];
    const int*   ei     = (const int*)d_in[1];
    const float* W1     = (const float*)d_in[2];
    const float* b1     = (const float*)d_in[3];
    const float* gamma1 = (const float*)d_in[4];
    const float* beta1  = (const float*)d_in[5];
    const float* mean1  = (const float*)d_in[6];
    const float* var1   = (const float*)d_in[7];
    const float* W2     = (const float*)d_in[8];
    const float* b2     = (const float*)d_in[9];
    const float* gamma2 = (const float*)d_in[10];
    const float* beta2  = (const float*)d_in[11];
    const float* mean2  = (const float*)d_in[12];
    const float* var2   = (const float*)d_in[13];
    const float* Wfc    = (const float*)d_in[14];
    const float* bfc    = (const float*)d_in[15];
    float* out = (float*)d_out;

    const int N = in_sizes[0] / FIN;   // 50000
    const int E = in_sizes[1] / 2;     // 800000
    const int NB = (N + 255) / 256;
    const int nslice = (E + (1 << SLICE_SHIFT) - 1) >> SLICE_SHIFT;  // 7 for E=800000

    // workspace layout (4-byte words, 16B-aligned sections)
    int* base = (int*)d_ws;
    size_t o = 0;
    int*   degi = base + o;                o = align4w(o + N + 1);   // +1: scan counter
    int*   cnt  = degi + N;
    float* dinv = (float*)(base + o);      o = align4w(o + N);
    int*   offs = base + o;                o = align4w(o + N + 1);
    int*   bsum = base + o;                o = align4w(o + 256);
    float* A1f  = (float*)(base + o);      o = align4w(o + H);
    float* B1f  = (float*)(base + o);      o = align4w(o + H);
    float* A2f  = (float*)(base + o);      o = align4w(o + H);
    float* B2f  = (float*)(base + o);      o = align4w(o + H);
    unsigned int* W1bhi = (unsigned int*)(base + o); o = align4w(o + 2048);
    unsigned int* W1blo = (unsigned int*)(base + o); o = align4w(o + 2048);
    unsigned int* W2bhi = (unsigned int*)(base + o); o = align4w(o + 8192);
    unsigned int* W2blo = (unsigned int*)(base + o); o = align4w(o + 8192);
    int*   rank = base + o;                o = align4w(o + (size_t)E);
    int*   csrS = base + o;                o = align4w(o + (size_t)E);
    unsigned short* xb = (unsigned short*)(base + o); o = align4w(o + (size_t)N * XP / 2);
    unsigned short* h2b = (unsigned short*)(base + o);

    zero_kernel<<<(N + 1 + 255) / 256, 256, 0, stream>>>(degi, N + 1);

    rank_kernel<<<(E + 255) / 256, 256, 0, stream>>>(
        ei, degi, rank, E,
        b1, mean1, var1, gamma1, beta1, b2, mean2, var2, gamma2, beta2,
        W1, W2, A1f, B1f, A2f, B2f, W1bhi, W1blo, W2bhi, W2blo);
    scanA_kernel<<<NB, 256, 0, stream>>>(degi, x, offs, bsum, cnt, dinv, xb, N);
    scatter8_kernel<<<((E + EPB - 1) / EPB) * 8, 256, 0, stream>>>(
        ei, rank, offs, bsum, csrS, E, nslice);

    gemm12f_kernel<<<(N + 15) / 16, 256, 0, stream>>>(
        xb, dinv, offs, bsum, csrS, W1bhi, W1blo, W2bhi, W2blo,
        A1f, B1f, A2f, h2b, N, E);
    gfinal_kernel<<<(N + 3) / 4, 256, 0, stream>>>(
        h2b, dinv, offs, bsum, csrS, B2f, Wfc, bfc, out, N, E);
}

// Round 12
// 161.349 us; speedup vs baseline: 1.2033x; 1.0003x over previous
//
#include <hip/hip_runtime.h>

#define EPS 1e-5f

constexpr int FIN = 22;   // input feature dim
constexpr int XP  = 32;   // padded x feature stride (= gemm1 K)
constexpr int H   = 128;  // hidden dim
constexpr int SLICE_SHIFT = 17;  // 131072 CSR entries (512KB) per slice
constexpr int EPB = 2048;        // edges per scatter block-chunk
constexpr int ALD = 136;         // LDS A-tile row stride (bf16 elems): 272B, 16B-aligned, 2-way banks

typedef __attribute__((ext_vector_type(8))) short bf16x8;   // 8 bf16 = 4 VGPRs
typedef __attribute__((ext_vector_type(4))) float f32x4;    // MFMA C/D

// bf16 helpers (bit-level, RN-even)
static __device__ __forceinline__ unsigned short f2bf(float f) {
    unsigned int u = __float_as_uint(f);
    unsigned int r = (u + 0x7fffu + ((u >> 16) & 1u)) >> 16;
    return (unsigned short)r;
}
static __device__ __forceinline__ float bf2f(unsigned short u) {
    return __uint_as_float(((unsigned int)u) << 16);
}
static __device__ __forceinline__ float bflo(unsigned int u) {
    return __uint_as_float(u << 16);
}
static __device__ __forceinline__ float bfhi(unsigned int u) {
    return __uint_as_float(u & 0xffff0000u);
}

// ---------------- zero degi + scan counter ----------------
__global__ void zero_kernel(int* __restrict__ p, int n) {
    int i = blockIdx.x * blockDim.x + threadIdx.x;
    if (i < n) p[i] = 0;
}

// ---------------- rank (degree+rank atomic pass) + BN prep + W1/W2 fragment prep ----------------
__global__ void rank_kernel(const int* __restrict__ ei, int* __restrict__ degi,
                            int* __restrict__ rank, int E,
                            const float* __restrict__ b1, const float* __restrict__ mean1,
                            const float* __restrict__ var1, const float* __restrict__ gamma1,
                            const float* __restrict__ beta1,
                            const float* __restrict__ b2, const float* __restrict__ mean2,
                            const float* __restrict__ var2, const float* __restrict__ gamma2,
                            const float* __restrict__ beta2,
                            const float* __restrict__ W1, const float* __restrict__ W2,
                            float* __restrict__ A1f, float* __restrict__ B1f,
                            float* __restrict__ A2f, float* __restrict__ B2f,
                            unsigned int* __restrict__ W1bhi, unsigned int* __restrict__ W1blo,
                            unsigned int* __restrict__ W2bhi, unsigned int* __restrict__ W2blo) {
    int e = blockIdx.x * blockDim.x + threadIdx.x;
    if (e < E) rank[e] = atomicAdd(&degi[ei[E + e]], 1);

    if (blockIdx.x == 0 && threadIdx.x < H) {
        int t = threadIdx.x;
        float A1 = gamma1[t] * rsqrtf(var1[t] + EPS);
        A1f[t] = A1;
        B1f[t] = (b1[t] - mean1[t]) * A1 + beta1[t];
        float A2 = gamma2[t] * rsqrtf(var2[t] + EPS);
        A2f[t] = A2;
        B2f[t] = (b2[t] - mean2[t]) * A2 + beta2[t];
    } else if (blockIdx.x >= 1 && blockIdx.x <= 8) {
        // W2 fragments: 2048 fragment-lanes
        int t = (blockIdx.x - 1) * 256 + threadIdx.x;
        int lane = t & 63, ks = (t >> 6) & 3, ct = t >> 8;
        int c  = ct * 16 + (lane & 15);
        int kb = ks * 32 + ((lane >> 4) << 3);
        unsigned int hi[4], lo[4];
#pragma unroll
        for (int d = 0; d < 4; ++d) {
            float f0 = W2[(kb + 2 * d) * H + c];
            float f1 = W2[(kb + 2 * d + 1) * H + c];
            unsigned short h0 = f2bf(f0), h1 = f2bf(f1);
            unsigned short l0 = f2bf(f0 - bf2f(h0)), l1 = f2bf(f1 - bf2f(h1));
            hi[d] = (unsigned int)h0 | ((unsigned int)h1 << 16);
            lo[d] = (unsigned int)l0 | ((unsigned int)l1 << 16);
        }
        *reinterpret_cast<uint4*>(W2bhi + (size_t)t * 4) = make_uint4(hi[0], hi[1], hi[2], hi[3]);
        *reinterpret_cast<uint4*>(W2blo + (size_t)t * 4) = make_uint4(lo[0], lo[1], lo[2], lo[3]);
    } else if (blockIdx.x == 9 || blockIdx.x == 10) {
        // W1 fragments: 512 fragment-lanes (K=32, zero-padded past FIN)
        int t = (blockIdx.x - 9) * 256 + threadIdx.x;
        int lane = t & 63, ct = t >> 6;
        int c  = ct * 16 + (lane & 15);
        int kb = (lane >> 4) << 3;
        unsigned int hi[4], lo[4];
#pragma unroll
        for (int d = 0; d < 4; ++d) {
            int k0 = kb + 2 * d, k1 = kb + 2 * d + 1;
            float f0 = (k0 < FIN) ? W1[k0 * H + c] : 0.0f;
            float f1 = (k1 < FIN) ? W1[k1 * H + c] : 0.0f;
            unsigned short h0 = f2bf(f0), h1 = f2bf(f1);
            unsigned short l0 = f2bf(f0 - bf2f(h0)), l1 = f2bf(f1 - bf2f(h1));
            hi[d] = (unsigned int)h0 | ((unsigned int)h1 << 16);
            lo[d] = (unsigned int)l0 | ((unsigned int)l1 << 16);
        }
        *reinterpret_cast<uint4*>(W1bhi + (size_t)t * 4) = make_uint4(hi[0], hi[1], hi[2], hi[3]);
        *reinterpret_cast<uint4*>(W1blo + (size_t)t * 4) = make_uint4(lo[0], lo[1], lo[2], lo[3]);
    }
}

// ---------------- scanA: per-block exclusive scan + dinv + xb=bf16(x*dinv); last block scans bsum ----
__global__ __launch_bounds__(256) void scanA_kernel(
    const int* __restrict__ degi, const float* __restrict__ x,
    int* __restrict__ offs, int* __restrict__ bsum, int* __restrict__ cnt,
    float* __restrict__ dinv, unsigned short* __restrict__ xb, int N) {
    __shared__ int sh[256];
    __shared__ int lastFlag;
    const int t = threadIdx.x;
    const int i = blockIdx.x * 256 + t;
    int v = (i < N) ? degi[i] : 0;
    sh[t] = v;
    __syncthreads();
    int val = v;
    for (int off = 1; off < 256; off <<= 1) {
        int add = (t >= off) ? sh[t - off] : 0;
        __syncthreads();
        val += add;
        sh[t] = val;
        __syncthreads();
    }
    if (i < N) offs[i] = val - v;          // exclusive within block (global base added by consumers)
    if (t == 255) bsum[blockIdx.x] = val;  // block total
    __syncthreads();                       // bsum store done block-wide
    if (t == 0) {
        __threadfence();                   // publish bsum before counting
        int c = atomicAdd(cnt, 1);
        lastFlag = (c == (int)gridDim.x - 1);
    }

    if (i < N) {
        float di = rsqrtf((float)v + 1.0f); // +1 self-loop
        dinv[i] = di;
        // vectorized x row read (11 x float2, 8B-aligned) + packed bf16 stores (4 x dwordx4)
        const float2* xr = reinterpret_cast<const float2*>(x + (size_t)i * FIN);
        unsigned int ob[16];
#pragma unroll
        for (int k2 = 0; k2 < 11; ++k2) {
            float2 v2 = xr[k2];
            unsigned int u0 = f2bf(v2.x * di);
            unsigned int u1 = f2bf(v2.y * di);
            ob[k2] = u0 | (u1 << 16);
        }
#pragma unroll
        for (int k2 = 11; k2 < 16; ++k2) ob[k2] = 0u;
        unsigned int* xo = reinterpret_cast<unsigned int*>(xb + (size_t)i * XP);
        *reinterpret_cast<uint4*>(xo + 0)  = make_uint4(ob[0], ob[1], ob[2], ob[3]);
        *reinterpret_cast<uint4*>(xo + 4)  = make_uint4(ob[4], ob[5], ob[6], ob[7]);
        *reinterpret_cast<uint4*>(xo + 8)  = make_uint4(ob[8], ob[9], ob[10], ob[11]);
        *reinterpret_cast<uint4*>(xo + 12) = make_uint4(ob[12], ob[13], ob[14], ob[15]);
    }
    __syncthreads();

    if (lastFlag) {                        // merged scanB: exclusive scan of bsum
        const int nb = gridDim.x;
        int v2 = (t < nb) ? atomicAdd(&bsum[t], 0) : 0;  // device-scope read
        sh[t] = v2;
        __syncthreads();
        int val2 = v2;
        for (int off = 1; off < 256; off <<= 1) {
            int add = (t >= off) ? sh[t - off] : 0;
            __syncthreads();
            val2 += add;
            sh[t] = val2;
            __syncthreads();
        }
        if (t < nb) bsum[t] = val2 - v2;
    }
}

// global CSR start of node i (i < N); use E for i == N
static __device__ __forceinline__ int off_at(const int* __restrict__ offs,
                                             const int* __restrict__ bsum,
                                             int i, int N, int E) {
    return (i < N) ? offs[i] + bsum[i >> 8] : E;
}

// ---------------- XCD-sliced CSR scatter ----------------
__global__ __launch_bounds__(256) void scatter8_kernel(
    const int* __restrict__ ei, const int* __restrict__ rank,
    const int* __restrict__ offs, const int* __restrict__ bsum,
    int* __restrict__ csrS, int E, int nslice) {
    const int r = blockIdx.x & 7;
    if (r >= nslice) return;
    const int chunk = blockIdx.x >> 3;
    const int e1 = min(chunk * EPB + EPB, E);
    for (int e = chunk * EPB + threadIdx.x; e < e1; e += 256) {
        int d = ei[E + e];
        int p = offs[d] + bsum[d >> 8] + rank[e];
        if ((p >> SLICE_SHIFT) == r) csrS[p] = ei[e];
    }
}
// CSR range of node d = [ off_at(d), off_at(d+1) )

// ---------------- fused: gather + MFMA gemm1 + BN1 + ReLU + MFMA gemm2 -> h2b ----------------
// Gather: 16-lane group per node; direct index loads (round-10 form), 4 rows in flight.
__global__ __launch_bounds__(256) void gemm12f_kernel(
    const unsigned short* __restrict__ xb, const float* __restrict__ dinv,
    const int* __restrict__ offs, const int* __restrict__ bsum,
    const int* __restrict__ csrS,
    const unsigned int* __restrict__ W1bhi, const unsigned int* __restrict__ W1blo,
    const unsigned int* __restrict__ W2bhi, const unsigned int* __restrict__ W2blo,
    const float* __restrict__ A1f, const float* __restrict__ B1f,
    const float* __restrict__ A2f,
    unsigned short* __restrict__ h2b, int N, int E) {
    __shared__ __align__(16) unsigned short Ahi[16 * ALD];
    __shared__ __align__(16) unsigned short Alo[16 * ALD];
    __shared__ float dil[16];
    const int tid = threadIdx.x;
    const int m0  = blockIdx.x * 16;

    // ---- gather into A-layout bf16 hi/lo (gemm1 A: k = feature 0..31), 4 loads in flight ----
    {
        const int g = tid >> 4, fl = tid & 15;
        const int node = m0 + g;
        if (node < N) {
            const int beg = off_at(offs, bsum, node, N, E);
            const int end = off_at(offs, bsum, node + 1, N, E);
            unsigned int v = *reinterpret_cast<const unsigned int*>(
                xb + (size_t)node * XP + fl * 2);
            float a0 = bflo(v), a1 = bfhi(v);   // self row (own dinv pre-folded in xb)
            int e = beg;
            for (; e + 3 < end; e += 4) {
                int s0 = csrS[e], s1 = csrS[e + 1], s2 = csrS[e + 2], s3 = csrS[e + 3];
                unsigned int v0 = *reinterpret_cast<const unsigned int*>(
                    xb + (size_t)s0 * XP + fl * 2);
                unsigned int v1 = *reinterpret_cast<const unsigned int*>(
                    xb + (size_t)s1 * XP + fl * 2);
                unsigned int v2 = *reinterpret_cast<const unsigned int*>(
                    xb + (size_t)s2 * XP + fl * 2);
                unsigned int v3 = *reinterpret_cast<const unsigned int*>(
                    xb + (size_t)s3 * XP + fl * 2);
                a0 += (bflo(v0) + bflo(v1)) + (bflo(v2) + bflo(v3));
                a1 += (bfhi(v0) + bfhi(v1)) + (bfhi(v2) + bfhi(v3));
            }
            for (; e < end; ++e) {
                int s = csrS[e];
                unsigned int v2 = *reinterpret_cast<const unsigned int*>(
                    xb + (size_t)s * XP + fl * 2);
                a0 += bflo(v2); a1 += bfhi(v2);
            }
            float di = dinv[node];
            if (fl == 0) dil[g] = di;
            a0 *= di; a1 *= di;
            unsigned short h0 = f2bf(a0), h1 = f2bf(a1);
            unsigned short l0 = f2bf(a0 - bf2f(h0)), l1 = f2bf(a1 - bf2f(h1));
            *reinterpret_cast<unsigned int*>(&Ahi[g * ALD + fl * 2]) =
                (unsigned int)h0 | ((unsigned int)h1 << 16);
            *reinterpret_cast<unsigned int*>(&Alo[g * ALD + fl * 2]) =
                (unsigned int)l0 | ((unsigned int)l1 << 16);
        }
    }
    __syncthreads();

    const int w    = tid >> 6;
    const int lane = tid & 63;
    const int arow = lane & 15;
    const int kgrp = lane >> 4;

    // ---- gemm1 MFMA (K=32, one step, 2 col-tiles/wave) ----
    f32x4 z = {0.f, 0.f, 0.f, 0.f};
    f32x4 acc1[2] = {z, z};
    {
        bf16x8 ah = *reinterpret_cast<const bf16x8*>(&Ahi[arow * ALD + kgrp * 8]);
        bf16x8 al = *reinterpret_cast<const bf16x8*>(&Alo[arow * ALD + kgrp * 8]);
#pragma unroll
        for (int t = 0; t < 2; ++t) {
            int idx = (w * 2 + t) * 64 + lane;
            bf16x8 bh = *reinterpret_cast<const bf16x8*>(W1bhi + (size_t)idx * 4);
            bf16x8 bl = *reinterpret_cast<const bf16x8*>(W1blo + (size_t)idx * 4);
            acc1[t] = __builtin_amdgcn_mfma_f32_16x16x32_bf16(ah, bh, acc1[t], 0, 0, 0);
            acc1[t] = __builtin_amdgcn_mfma_f32_16x16x32_bf16(ah, bl, acc1[t], 0, 0, 0);
            acc1[t] = __builtin_amdgcn_mfma_f32_16x16x32_bf16(al, bh, acc1[t], 0, 0, 0);
        }
    }
    __syncthreads();   // all gemm1 A-reads done before overwrite

    // ---- epilogue-1: BN1+ReLU, hi/lo split, write back as gemm2's A (k = feature 0..127) ----
#pragma unroll
    for (int t = 0; t < 2; ++t) {
        int col = (w * 2 + t) * 16 + arow;
        float a1c = A1f[col], b1c = B1f[col];
#pragma unroll
        for (int r = 0; r < 4; ++r) {
            int row = kgrp * 4 + r;
            float h = fmaxf(acc1[t][r] * a1c + b1c, 0.f);
            unsigned short hh = f2bf(h);
            unsigned short hl = f2bf(h - bf2f(hh));
            Ahi[row * ALD + col] = hh;
            Alo[row * ALD + col] = hl;
        }
    }
    __syncthreads();

    // ---- gemm2 MFMA (K=128, 4 steps, 2 col-tiles/wave) ----
    f32x4 acc2[2] = {z, z};
    for (int ks = 0; ks < 4; ++ks) {
        bf16x8 ah = *reinterpret_cast<const bf16x8*>(&Ahi[arow * ALD + ks * 32 + kgrp * 8]);
        bf16x8 al = *reinterpret_cast<const bf16x8*>(&Alo[arow * ALD + ks * 32 + kgrp * 8]);
#pragma unroll
        for (int t = 0; t < 2; ++t) {
            int idx = ((w * 2 + t) * 4 + ks) * 64 + lane;
            bf16x8 bh = *reinterpret_cast<const bf16x8*>(W2bhi + (size_t)idx * 4);
            bf16x8 bl = *reinterpret_cast<const bf16x8*>(W2blo + (size_t)idx * 4);
            acc2[t] = __builtin_amdgcn_mfma_f32_16x16x32_bf16(ah, bh, acc2[t], 0, 0, 0);
            acc2[t] = __builtin_amdgcn_mfma_f32_16x16x32_bf16(ah, bl, acc2[t], 0, 0, 0);
            acc2[t] = __builtin_amdgcn_mfma_f32_16x16x32_bf16(al, bh, acc2[t], 0, 0, 0);
        }
    }

    // ---- epilogue-2: h2b = bf16(acc2 * A2[col] * dinv[node]) ----
#pragma unroll
    for (int t = 0; t < 2; ++t) {
        int col = (w * 2 + t) * 16 + arow;
        float sc = A2f[col];
#pragma unroll
        for (int r = 0; r < 4; ++r) {
            int row = kgrp * 4 + r;
            int node = m0 + row;
            if (node < N)
                h2b[(size_t)node * H + col] = f2bf(acc2[t][r] * sc * dil[row]);
        }
    }
}

// ---------------- fused: layer-2 gather (pure row sum) + BN2 + ReLU + FC + sigmoid ----------------
// wave = 4 groups x 16 lanes; 2-row body (round-5/10 shape, best measured)
__global__ __launch_bounds__(256) void gfinal_kernel(
    const unsigned short* __restrict__ h2b, const float* __restrict__ dinv,
    const int* __restrict__ offs, const int* __restrict__ bsum,
    const int* __restrict__ csrS,
    const float* __restrict__ B2f, const float* __restrict__ Wfc,
    const float* __restrict__ bfc, float* __restrict__ out, int N, int E) {
    const int tid  = threadIdx.x;
    const int node = blockIdx.x * 4 + (tid >> 6);
    const int lane = tid & 63;
    if (node >= N) return;
    const int g  = lane >> 4;      // group 0..3
    const int fl = lane & 15;      // lane in group
    const int f0 = fl * 8;
    const int beg = off_at(offs, bsum, node, N, E);
    const int end = off_at(offs, bsum, node + 1, N, E);

    float acc[8];
#pragma unroll
    for (int j = 0; j < 8; ++j) acc[j] = 0.0f;

    if (g == 0) {  // self row, weight 1
        uint4 v = *reinterpret_cast<const uint4*>(h2b + (size_t)node * H + f0);
        acc[0] = bflo(v.x); acc[1] = bfhi(v.x);
        acc[2] = bflo(v.y); acc[3] = bfhi(v.y);
        acc[4] = bflo(v.z); acc[5] = bfhi(v.z);
        acc[6] = bflo(v.w); acc[7] = bfhi(v.w);
    }
    int e = beg + g;
    for (; e + 4 < end; e += 8) {
        int s0 = csrS[e];
        int s1 = csrS[e + 4];
        uint4 v0 = *reinterpret_cast<const uint4*>(h2b + (size_t)s0 * H + f0);
        uint4 v1 = *reinterpret_cast<const uint4*>(h2b + (size_t)s1 * H + f0);
        acc[0] += bflo(v0.x) + bflo(v1.x); acc[1] += bfhi(v0.x) + bfhi(v1.x);
        acc[2] += bflo(v0.y) + bflo(v1.y); acc[3] += bfhi(v0.y) + bfhi(v1.y);
        acc[4] += bflo(v0.z) + bflo(v1.z); acc[5] += bfhi(v0.z) + bfhi(v1.z);
        acc[6] += bflo(v0.w) + bflo(v1.w); acc[7] += bfhi(v0.w) + bfhi(v1.w);
    }
    if (e < end) {
        int s = csrS[e];
        uint4 v = *reinterpret_cast<const uint4*>(h2b + (size_t)s * H + f0);
        acc[0] += bflo(v.x); acc[1] += bfhi(v.x);
        acc[2] += bflo(v.y); acc[3] += bfhi(v.y);
        acc[4] += bflo(v.z); acc[5] += bfhi(v.z);
        acc[6] += bflo(v.w); acc[7] += bfhi(v.w);
    }
#pragma unroll
    for (int j = 0; j < 8; ++j) {
        acc[j] += __shfl_xor(acc[j], 16);
        acc[j] += __shfl_xor(acc[j], 32);
    }
    const float di = dinv[node];
    float p = 0.0f;
#pragma unroll
    for (int j = 0; j < 8; ++j)
        p += fmaxf(acc[j] * di + B2f[f0 + j], 0.0f) * Wfc[f0 + j];
#pragma unroll
    for (int off = 1; off < 16; off <<= 1) p += __shfl_xor(p, off);
    if (lane == 0) out[node] = 1.0f / (1.0f + expf(-(p + bfc[0])));
}

static inline size_t align4w(size_t w) { return (w + 3) & ~(size_t)3; }  // 16B align (words)

extern "C" void kernel_launch(void* const* d_in, const int* in_sizes, int n_in,
                              void* d_out, int out_size, void* d_ws, size_t ws_size,
                              hipStream_t stream) {
    const float* x      = (const float*)d_in[0];
    const int*   ei     = (const int*)d_in[1];
    const float* W1     = (const float*)d_in[2];
    const float* b1     = (const float*)d_in[3];
    const float* gamma1 = (const float*)d_in[4];
    const float* beta1  = (const float*)d_in[5];
    const float* mean1  = (const float*)d_in[6];
    const float* var1   = (const float*)d_in[7];
    const float* W2     = (const float*)d_in[8];
    const float* b2     = (const float*)d_in[9];
    const float* gamma2 = (const float*)d_in[10];
    const float* beta2  = (const float*)d_in[11];
    const float* mean2  = (const float*)d_in[12];
    const float* var2   = (const float*)d_in[13];
    const float* Wfc    = (const float*)d_in[14];
    const float* bfc    = (const float*)d_in[15];
    float* out = (float*)d_out;

    const int N = in_sizes[0] / FIN;   // 50000
    const int E = in_sizes[1] / 2;     // 800000
    const int NB = (N + 255) / 256;
    const int nslice = (E + (1 << SLICE_SHIFT) - 1) >> SLICE_SHIFT;  // 7 for E=800000

    // workspace layout (4-byte words, 16B-aligned sections)
    int* base = (int*)d_ws;
    size_t o = 0;
    int*   degi = base + o;                o = align4w(o + N + 1);   // +1: scan counter
    int*   cnt  = degi + N;
    float* dinv = (float*)(base + o);      o = align4w(o + N);
    int*   offs = base + o;                o = align4w(o + N + 1);
    int*   bsum = base + o;                o = align4w(o + 256);
    float* A1f  = (float*)(base + o);      o = align4w(o + H);
    float* B1f  = (float*)(base + o);      o = align4w(o + H);
    float* A2f  = (float*)(base + o);      o = align4w(o + H);
    float* B2f  = (float*)(base + o);      o = align4w(o + H);
    unsigned int* W1bhi = (unsigned int*)(base + o); o = align4w(o + 2048);
    unsigned int* W1blo = (unsigned int*)(base + o); o = align4w(o + 2048);
    unsigned int* W2bhi = (unsigned int*)(base + o); o = align4w(o + 8192);
    unsigned int* W2blo = (unsigned int*)(base + o); o = align4w(o + 8192);
    int*   rank = base + o;                o = align4w(o + (size_t)E);
    int*   csrS = base + o;                o = align4w(o + (size_t)E);
    unsigned short* xb = (unsigned short*)(base + o); o = align4w(o + (size_t)N * XP / 2);
    unsigned short* h2b = (unsigned short*)(base + o);

    zero_kernel<<<(N + 1 + 255) / 256, 256, 0, stream>>>(degi, N + 1);

    rank_kernel<<<(E + 255) / 256, 256, 0, stream>>>(
        ei, degi, rank, E,
        b1, mean1, var1, gamma1, beta1, b2, mean2, var2, gamma2, beta2,
        W1, W2, A1f, B1f, A2f, B2f, W1bhi, W1blo, W2bhi, W2blo);
    scanA_kernel<<<NB, 256, 0, stream>>>(degi, x, offs, bsum, cnt, dinv, xb, N);
    scatter8_kernel<<<((E + EPB - 1) / EPB) * 8, 256, 0, stream>>>(
        ei, rank, offs, bsum, csrS, E, nslice);

    gemm12f_kernel<<<(N + 15) / 16, 256, 0, stream>>>(
        xb, dinv, offs, bsum, csrS, W1bhi, W1blo, W2bhi, W2blo,
        A1f, B1f, A2f, h2b, N, E);
    gfinal_kernel<<<(N + 3) / 4, 256, 0, stream>>>(
        h2b, dinv, offs, bsum, csrS, B2f, Wfc, bfc, out, N, E);
}